// Round 1
// baseline (287.084 us; speedup 1.0000x reference)
//
#include <hip/hip_runtime.h>
#include <hip/hip_bf16.h>

// Hedgehog linear attention, B=1, L=1024, D=1024, H=16, HD=64, FD=64.
// Pipeline (all fp32 this round):
//  1) qkv_gemm:  Q,K,V = x @ {Wq,Wk,Wv}          (fused, shared A-tiles)
//  2) featmap:   qf = [softmax(Kq^T q), softmax(-Kq^T q)] clamped; same for kf
//  3) chunk_sums: per (h, chunk c of 64): Sc[d][f] = sum_t v[t][d]*kf[t][f], ksum[f]
//  4) prefix_scan: exclusive prefix over chunks -> Sp, kp
//  5) chunk_out: O = (Qf Kf^T masked) V + Qf Sp^T, z = qf.(kp + cumsum-intra), Y = O/z
//  6) sgemm64:   out = Y @ Wo

#define LL 1024
#define NH 16
#define HD 64
#define NC 16   // chunks
#define CS 64   // chunk size

__global__ __launch_bounds__(256) void qkv_gemm(const float* __restrict__ A,
                                                const float* __restrict__ Bq,
                                                const float* __restrict__ Bk,
                                                const float* __restrict__ Bv,
                                                float* __restrict__ Cq,
                                                float* __restrict__ Ck,
                                                float* __restrict__ Cv) {
    __shared__ float As[16][68];
    __shared__ float Bqs[16][68], Bks[16][68], Bvs[16][68];
    const int tid = threadIdx.x;
    const int bm = blockIdx.y * 64, bn = blockIdx.x * 64;
    const int tm = (tid >> 4) << 2, tn = (tid & 15) << 2;
    const int ar = tid >> 2, ac = (tid & 3) << 2;      // A tile 64x16
    const int br = tid >> 4, bc = (tid & 15) << 2;     // B tile 16x64
    float aq[4][4] = {{0.f}}, ak[4][4] = {{0.f}}, av_[4][4] = {{0.f}};
    for (int k0 = 0; k0 < 1024; k0 += 16) {
        float4 a4 = *(const float4*)&A[(bm + ar) * 1024 + k0 + ac];
        float4 q4 = *(const float4*)&Bq[(k0 + br) * 1024 + bn + bc];
        float4 k4 = *(const float4*)&Bk[(k0 + br) * 1024 + bn + bc];
        float4 v4 = *(const float4*)&Bv[(k0 + br) * 1024 + bn + bc];
        As[ac + 0][ar] = a4.x; As[ac + 1][ar] = a4.y;
        As[ac + 2][ar] = a4.z; As[ac + 3][ar] = a4.w;
        *(float4*)&Bqs[br][bc] = q4;
        *(float4*)&Bks[br][bc] = k4;
        *(float4*)&Bvs[br][bc] = v4;
        __syncthreads();
#pragma unroll
        for (int kk = 0; kk < 16; kk++) {
            float4 a4r = *(const float4*)&As[kk][tm];
            float4 q4r = *(const float4*)&Bqs[kk][tn];
            float4 k4r = *(const float4*)&Bks[kk][tn];
            float4 v4r = *(const float4*)&Bvs[kk][tn];
            float a[4] = {a4r.x, a4r.y, a4r.z, a4r.w};
            float bq[4] = {q4r.x, q4r.y, q4r.z, q4r.w};
            float bk[4] = {k4r.x, k4r.y, k4r.z, k4r.w};
            float bv[4] = {v4r.x, v4r.y, v4r.z, v4r.w};
#pragma unroll
            for (int i = 0; i < 4; i++) {
#pragma unroll
                for (int j = 0; j < 4; j++) {
                    aq[i][j] += a[i] * bq[j];
                    ak[i][j] += a[i] * bk[j];
                    av_[i][j] += a[i] * bv[j];
                }
            }
        }
        __syncthreads();
    }
#pragma unroll
    for (int i = 0; i < 4; i++) {
#pragma unroll
        for (int j = 0; j < 4; j++) {
            const int idx = (bm + tm + i) * 1024 + bn + tn + j;
            Cq[idx] = aq[i][j];
            Ck[idx] = ak[i][j];
            Cv[idx] = av_[i][j];
        }
    }
}

// plain single-output GEMM (used for the final Y @ Wo)
__global__ __launch_bounds__(256) void sgemm64(const float* __restrict__ A,
                                               const float* __restrict__ B,
                                               float* __restrict__ C) {
    __shared__ float As[16][68];
    __shared__ float Bs[16][68];
    const int tid = threadIdx.x;
    const int bm = blockIdx.y * 64, bn = blockIdx.x * 64;
    const int tm = (tid >> 4) << 2, tn = (tid & 15) << 2;
    const int ar = tid >> 2, ac = (tid & 3) << 2;
    const int br = tid >> 4, bc = (tid & 15) << 2;
    float acc[4][4] = {{0.f}};
    for (int k0 = 0; k0 < 1024; k0 += 16) {
        float4 a4 = *(const float4*)&A[(bm + ar) * 1024 + k0 + ac];
        float4 b4 = *(const float4*)&B[(k0 + br) * 1024 + bn + bc];
        As[ac + 0][ar] = a4.x; As[ac + 1][ar] = a4.y;
        As[ac + 2][ar] = a4.z; As[ac + 3][ar] = a4.w;
        *(float4*)&Bs[br][bc] = b4;
        __syncthreads();
#pragma unroll
        for (int kk = 0; kk < 16; kk++) {
            float4 a4r = *(const float4*)&As[kk][tm];
            float4 b4r = *(const float4*)&Bs[kk][tn];
            float a[4] = {a4r.x, a4r.y, a4r.z, a4r.w};
            float b[4] = {b4r.x, b4r.y, b4r.z, b4r.w};
#pragma unroll
            for (int i = 0; i < 4; i++)
#pragma unroll
                for (int j = 0; j < 4; j++)
                    acc[i][j] += a[i] * b[j];
        }
        __syncthreads();
    }
#pragma unroll
    for (int i = 0; i < 4; i++)
#pragma unroll
        for (int j = 0; j < 4; j++)
            C[(bm + tm + i) * 1024 + bn + tn + j] = acc[i][j];
}

// f[h][l][fi] = sum_d Kmat[h][d][fi] * QK[l][h*64+d]; out = [softmax(f), softmax(-f)] clamped
__global__ __launch_bounds__(256) void featmap(const float* __restrict__ QK,
                                               const float* __restrict__ Kmat,
                                               float* __restrict__ feat) {
    const int h = blockIdx.y;
    const int l = blockIdx.x * 4 + threadIdx.y;
    const int f = threadIdx.x;  // 0..63, one wave per l
    __shared__ float qs[4][64];
    qs[threadIdx.y][f] = QK[l * 1024 + h * 64 + f];
    __syncthreads();
    const float* Km = Kmat + h * 4096 + f;
    float acc = 0.f;
#pragma unroll 8
    for (int d = 0; d < 64; d++) acc += qs[threadIdx.y][d] * Km[d * 64];
    float m1 = acc, m2 = -acc;
#pragma unroll
    for (int off = 32; off; off >>= 1) {
        m1 = fmaxf(m1, __shfl_xor(m1, off));
        m2 = fmaxf(m2, __shfl_xor(m2, off));
    }
    float e1 = expf(acc - m1), e2 = expf(-acc - m2);
    float s1 = e1, s2 = e2;
#pragma unroll
    for (int off = 32; off; off >>= 1) {
        s1 += __shfl_xor(s1, off);
        s2 += __shfl_xor(s2, off);
    }
    float* o = feat + (h * 1024 + l) * 128;
    o[f] = fmaxf(e1 / s1, 1e-12f);
    o[64 + f] = fmaxf(e2 / s2, 1e-12f);
}

// Sc[h][c][d][f] = sum_{t in chunk} V[t][d] * kf[t][f];  ksum[h][c][f] = sum_t kf[t][f]
__global__ __launch_bounds__(256) void chunk_sums(const float* __restrict__ kf,
                                                  const float* __restrict__ V,
                                                  float* __restrict__ Sc,
                                                  float* __restrict__ ksum) {
    const int h = blockIdx.y, c = blockIdx.x, tid = threadIdx.x;
    const int l0 = c * CS;
    __shared__ float kfs[64][132];
    __shared__ float vs[64][68];
    const float4* k4 = (const float4*)(kf + (h * 1024 + l0) * 128);
    for (int i = tid; i < 2048; i += 256) {
        int r = i >> 5, c4 = i & 31;
        *(float4*)&kfs[r][c4 * 4] = k4[i];
    }
    for (int i = tid; i < 1024; i += 256) {
        int r = i >> 4, c4 = i & 15;
        *(float4*)&vs[r][c4 * 4] = *(const float4*)&V[(l0 + r) * 1024 + h * 64 + c4 * 4];
    }
    __syncthreads();
    const int d0 = (tid & 7) << 3, f0 = (tid >> 3) << 2;  // 8x4 tile of (d,f)
    float acc[8][4] = {{0.f}};
    for (int t = 0; t < 64; t++) {
        float4 va = *(const float4*)&vs[t][d0];
        float4 vb = *(const float4*)&vs[t][d0 + 4];
        float4 kc = *(const float4*)&kfs[t][f0];
        float vv[8] = {va.x, va.y, va.z, va.w, vb.x, vb.y, vb.z, vb.w};
        float kv[4] = {kc.x, kc.y, kc.z, kc.w};
#pragma unroll
        for (int i = 0; i < 8; i++)
#pragma unroll
            for (int j = 0; j < 4; j++)
                acc[i][j] += vv[i] * kv[j];
    }
    float* o = Sc + (h * NC + c) * 8192;
#pragma unroll
    for (int i = 0; i < 8; i++)
#pragma unroll
        for (int j = 0; j < 4; j++)
            o[(d0 + i) * 128 + f0 + j] = acc[i][j];
    if (tid < 128) {
        float s = 0.f;
        for (int t = 0; t < 64; t++) s += kfs[t][tid];
        ksum[(h * NC + c) * 128 + tid] = s;
    }
}

__global__ __launch_bounds__(256) void prefix_scan(const float* __restrict__ Sc,
                                                   float* __restrict__ Sp,
                                                   const float* __restrict__ ksum,
                                                   float* __restrict__ kp) {
    const int h = blockIdx.x, tid = threadIdx.x;
    for (int e = tid; e < 8192; e += 256) {
        float run = 0.f;
        for (int c = 0; c < NC; c++) {
            int idx = (h * NC + c) * 8192 + e;
            Sp[idx] = run;
            run += Sc[idx];
        }
    }
    if (tid < 128) {
        float run = 0.f;
        for (int c = 0; c < NC; c++) {
            int idx = (h * NC + c) * 128 + tid;
            kp[idx] = run;
            run += ksum[idx];
        }
    }
}

__global__ __launch_bounds__(256) void chunk_out(const float* __restrict__ qf,
                                                 const float* __restrict__ kf,
                                                 const float* __restrict__ V,
                                                 const float* __restrict__ Sp,
                                                 const float* __restrict__ kp,
                                                 float* __restrict__ Y) {
    const int h = blockIdx.y, c = blockIdx.x, tid = threadIdx.x;
    const int l0 = c * CS;
    __shared__ float Qs[64][132];
    __shared__ float Ks[64][132];   // Kf chunk, later reused for Sp
    __shared__ float Vs[64][68];
    __shared__ float Am[64][68];
    __shared__ float kpre[128];
    __shared__ float invz[64];

    {
        const float4* q4 = (const float4*)(qf + (h * 1024 + l0) * 128);
        const float4* k4 = (const float4*)(kf + (h * 1024 + l0) * 128);
        for (int i = tid; i < 2048; i += 256) {
            int r = i >> 5, c4 = i & 31;
            *(float4*)&Qs[r][c4 * 4] = q4[i];
            *(float4*)&Ks[r][c4 * 4] = k4[i];
        }
        for (int i = tid; i < 1024; i += 256) {
            int r = i >> 4, c4 = i & 15;
            *(float4*)&Vs[r][c4 * 4] = *(const float4*)&V[(l0 + r) * 1024 + h * 64 + c4 * 4];
        }
        if (tid < 128) kpre[tid] = kp[(h * NC + c) * 128 + tid];
    }
    __syncthreads();

    const int t0 = (tid >> 4) << 2;
    const int s0 = (tid & 15) << 2;
    {
        float a[4][4] = {{0.f}};
        for (int f = 0; f < 128; f++) {
            float qv[4], kv[4];
#pragma unroll
            for (int i = 0; i < 4; i++) qv[i] = Qs[t0 + i][f];
#pragma unroll
            for (int j = 0; j < 4; j++) kv[j] = Ks[s0 + j][f];
#pragma unroll
            for (int i = 0; i < 4; i++)
#pragma unroll
                for (int j = 0; j < 4; j++)
                    a[i][j] += qv[i] * kv[j];
        }
#pragma unroll
        for (int i = 0; i < 4; i++)
#pragma unroll
            for (int j = 0; j < 4; j++)
                Am[t0 + i][s0 + j] = (s0 + j <= t0 + i) ? a[i][j] : 0.0f;
    }
    __syncthreads();
    {
        // overwrite Ks with S_prev (64 x 128)
        const float4* s4 = (const float4*)(Sp + (h * NC + c) * 8192);
        for (int i = tid; i < 2048; i += 256) {
            int r = i >> 5, c4 = i & 31;
            *(float4*)&Ks[r][c4 * 4] = s4[i];
        }
        if (tid < 64) {
            const int t = tid;
            float z = 1e-12f;
            for (int s = 0; s < 64; s++) z += Am[t][s];          // masked row sum (cumsum-intra at t)
            for (int f = 0; f < 128; f++) z += Qs[t][f] * kpre[f];
            invz[t] = 1.0f / z;
        }
    }
    __syncthreads();
    {
        const int d0 = s0;
        float o[4][4] = {{0.f}};
        for (int s = 0; s < 64; s++) {
            float av[4], vv[4];
#pragma unroll
            for (int i = 0; i < 4; i++) av[i] = Am[t0 + i][s];
#pragma unroll
            for (int j = 0; j < 4; j++) vv[j] = Vs[s][d0 + j];
#pragma unroll
            for (int i = 0; i < 4; i++)
#pragma unroll
                for (int j = 0; j < 4; j++)
                    o[i][j] += av[i] * vv[j];
        }
        for (int f = 0; f < 128; f++) {
            float qv[4], sv[4];
#pragma unroll
            for (int i = 0; i < 4; i++) qv[i] = Qs[t0 + i][f];
#pragma unroll
            for (int j = 0; j < 4; j++) sv[j] = Ks[d0 + j][f];
#pragma unroll
            for (int i = 0; i < 4; i++)
#pragma unroll
                for (int j = 0; j < 4; j++)
                    o[i][j] += qv[i] * sv[j];
        }
#pragma unroll
        for (int i = 0; i < 4; i++)
#pragma unroll
            for (int j = 0; j < 4; j++)
                Y[(l0 + t0 + i) * 1024 + h * 64 + d0 + j] = o[i][j] * invz[t0 + i];
    }
}

extern "C" void kernel_launch(void* const* d_in, const int* in_sizes, int n_in,
                              void* d_out, int out_size, void* d_ws, size_t ws_size,
                              hipStream_t stream) {
    const float* x  = (const float*)d_in[0];
    const float* Wq = (const float*)d_in[1];
    const float* Wk = (const float*)d_in[2];
    const float* Wv = (const float*)d_in[3];
    const float* Wo = (const float*)d_in[4];
    const float* Kq = (const float*)d_in[5];
    const float* Kk = (const float*)d_in[6];
    float* out = (float*)d_out;
    float* ws = (float*)d_ws;

    const size_t M1 = 1024 * 1024;
    // compact layout with stream-ordered aliasing (Q,K dead after featmap; Sc reuses them)
    float* V   = ws;               // 1M floats
    float* qf  = ws + 1 * M1;      // 2M
    float* kfb = ws + 3 * M1;      // 2M
    float* Q   = ws + 5 * M1;      // 1M  (aliased by Sc later)
    float* K   = ws + 6 * M1;      // 1M  (aliased by Sc later)
    float* Sc  = ws + 5 * M1;      // 2M  (over Q+K)
    float* Sp  = ws + 7 * M1;      // 2M
    float* Y   = ws + 9 * M1;      // 1M
    float* ksum = ws + 10 * M1;            // 32768
    float* kp   = ws + 10 * M1 + 32768;    // 32768
    if (ws_size < (10 * M1 + 65536) * sizeof(float)) return;  // workspace too small

    dim3 g16(16, 16);
    qkv_gemm<<<g16, 256, 0, stream>>>(x, Wq, Wk, Wv, Q, K, V);
    featmap<<<dim3(256, 16), dim3(64, 4), 0, stream>>>(Q, Kq, qf);
    featmap<<<dim3(256, 16), dim3(64, 4), 0, stream>>>(K, Kk, kfb);
    chunk_sums<<<dim3(NC, NH), 256, 0, stream>>>(kfb, V, Sc, ksum);
    prefix_scan<<<NH, 256, 0, stream>>>(Sc, Sp, ksum, kp);
    chunk_out<<<dim3(NC, NH), 256, 0, stream>>>(qf, kfb, V, Sp, kp, Y);
    sgemm64<<<g16, 256, 0, stream>>>(Y, Wo, out);
}

// Round 2
// 98.631 us; speedup vs baseline: 2.9107x; 2.9107x over previous
//
#include <hip/hip_runtime.h>
#include <hip/hip_bf16.h>

// Hedgehog linear attention, B=1, L=1024, D=1024, H=16, HD=64, FD=64.
// Round 2: bf16 MFMA GEMMs for QKV and final projection.
//  0) transpose+convert Wq/Wk/Wv/Wo -> bf16 W^T; convert x -> bf16
//  1) gemm_bt_bf16<3>: Q,K,V = x @ W (MFMA 16x16x32, 64x64 tiles, swizzled LDS)
//  2) featmap (fused q/k): softmax feature maps (fp32)
//  3) chunk_sums -> prefix_scan -> chunk_out (fp32, Y emitted as bf16)
//  4) gemm_bt_bf16<1>: out = Y @ Wo

#define NH 16
#define NC 16
#define CS 64

using short8 = __attribute__((ext_vector_type(8))) short;
using f32x4  = __attribute__((ext_vector_type(4))) float;
typedef const __attribute__((address_space(1))) char* gptr1;
typedef __attribute__((address_space(3))) char* lptr3;

static __device__ __forceinline__ unsigned short bf16bits(float x) {
    __hip_bfloat16 h = __float2bfloat16(x);
    return __builtin_bit_cast(unsigned short, h);
}

// ---- weight transpose + convert: src f32 (K=1024 x N=1024) -> dst bf16 (N x K)
__global__ __launch_bounds__(256) void wt_convert(const float* __restrict__ s0,
                                                  const float* __restrict__ s1,
                                                  const float* __restrict__ s2,
                                                  const float* __restrict__ s3,
                                                  __hip_bfloat16* __restrict__ d0,
                                                  __hip_bfloat16* __restrict__ d1,
                                                  __hip_bfloat16* __restrict__ d2,
                                                  __hip_bfloat16* __restrict__ d3) {
    const float* src = (blockIdx.z == 0) ? s0 : (blockIdx.z == 1) ? s1 : (blockIdx.z == 2) ? s2 : s3;
    __hip_bfloat16* dst = (blockIdx.z == 0) ? d0 : (blockIdx.z == 1) ? d1 : (blockIdx.z == 2) ? d2 : d3;
    __shared__ float tile[32][33];
    const int bx = blockIdx.x * 32;  // n base
    const int by = blockIdx.y * 32;  // k base
    const int tx = threadIdx.x, ty = threadIdx.y;  // 32 x 8
#pragma unroll
    for (int i = 0; i < 32; i += 8)
        tile[ty + i][tx] = src[(by + ty + i) * 1024 + bx + tx];
    __syncthreads();
#pragma unroll
    for (int i = 0; i < 32; i += 8)
        dst[(size_t)(bx + ty + i) * 1024 + by + tx] = __float2bfloat16(tile[tx][ty + i]);
}

// ---- x convert f32 -> bf16 (1M elems)
__global__ __launch_bounds__(256) void x_convert(const float* __restrict__ s,
                                                 __hip_bfloat16* __restrict__ d) {
    const int i = (blockIdx.x * 256 + threadIdx.x) * 4;
    float4 v = *(const float4*)(s + i);
    ushort4 o;
    o.x = bf16bits(v.x); o.y = bf16bits(v.y); o.z = bf16bits(v.z); o.w = bf16bits(v.w);
    *(ushort4*)((unsigned short*)d + i) = o;
}

// ---- bf16 MFMA GEMM, A (M x K row-major), B^T (N x K row-major), C f32 (M x N)
// tile 64x64, BK=64, K=1024 fixed. NMAT=3 selects among B0/B1/B2 via blockIdx.x>>4.
template<int NMAT>
__global__ __launch_bounds__(256) void gemm_bt_bf16(const __hip_bfloat16* __restrict__ A,
                                                    const __hip_bfloat16* __restrict__ B0,
                                                    const __hip_bfloat16* __restrict__ B1,
                                                    const __hip_bfloat16* __restrict__ B2,
                                                    float* __restrict__ C0,
                                                    float* __restrict__ C1,
                                                    float* __restrict__ C2) {
    __shared__ __align__(16) char Abuf[64 * 128];
    __shared__ __align__(16) char Bbuf[64 * 128];
    const int tid = threadIdx.x;
    const int bm = blockIdx.y * 64;
    int nb = blockIdx.x;
    const __hip_bfloat16* B = B0;
    float* C = C0;
    if (NMAT == 3) {
        const int which = nb >> 4;
        nb &= 15;
        if (which == 1) { B = B1; C = C1; }
        else if (which == 2) { B = B2; C = C2; }
    }
    const int bn = nb * 64;

    const int srow = tid >> 3;            // 0..31 (staging row within half)
    const int scol0 = (tid & 7) * 16;     // staging byte col
    const int wid = tid >> 6, lane = tid & 63;
    const int g = lane >> 4, r16 = lane & 15;
    const int wr = wid >> 1, wc = wid & 1;
    const char* Ab = (const char*)A;
    const char* Bb = (const char*)B;

    f32x4 acc[2][2] = {};

    for (int kt = 0; kt < 16; kt++) {
        const int kbyte = kt * 128;
#pragma unroll
        for (int hh = 0; hh < 2; hh++) {
            const int row = hh * 32 + srow;
            const int sc = scol0 ^ ((row & 7) << 4);  // pre-swizzled global source (rule 21)
            __builtin_amdgcn_global_load_lds((gptr1)(Ab + (size_t)(bm + row) * 2048 + kbyte + sc),
                                             (lptr3)(Abuf + hh * 4096 + wid * 1024), 16, 0, 0);
            __builtin_amdgcn_global_load_lds((gptr1)(Bb + (size_t)(bn + row) * 2048 + kbyte + sc),
                                             (lptr3)(Bbuf + hh * 4096 + wid * 1024), 16, 0, 0);
        }
        __syncthreads();
#pragma unroll
        for (int ks = 0; ks < 2; ks++) {
            short8 af[2], bfr[2];
#pragma unroll
            for (int m = 0; m < 2; m++) {
                const int row = wr * 32 + m * 16 + r16;
                af[m] = *(const short8*)(Abuf + row * 128 + ((ks * 64 + g * 16) ^ ((row & 7) << 4)));
            }
#pragma unroll
            for (int n = 0; n < 2; n++) {
                const int row = wc * 32 + n * 16 + r16;
                bfr[n] = *(const short8*)(Bbuf + row * 128 + ((ks * 64 + g * 16) ^ ((row & 7) << 4)));
            }
#pragma unroll
            for (int m = 0; m < 2; m++)
#pragma unroll
                for (int n = 0; n < 2; n++)
                    acc[m][n] = __builtin_amdgcn_mfma_f32_16x16x32_bf16(af[m], bfr[n], acc[m][n], 0, 0, 0);
        }
        __syncthreads();
    }
#pragma unroll
    for (int m = 0; m < 2; m++)
#pragma unroll
        for (int n = 0; n < 2; n++)
#pragma unroll
            for (int i = 0; i < 4; i++) {
                const int row = bm + wr * 32 + m * 16 + g * 4 + i;   // m89-verified C/D map
                const int col = bn + wc * 32 + n * 16 + r16;
                C[(size_t)row * 1024 + col] = acc[m][n][i];
            }
}

// ---- feature map: f[h][l][fi] = sum_d Kmat[h][d][fi]*QK[l][h*64+d]; [softmax(f),softmax(-f)] clamped
__global__ __launch_bounds__(256) void featmap(const float* __restrict__ Qm,
                                               const float* __restrict__ Km,
                                               const float* __restrict__ Kq,
                                               const float* __restrict__ Kk,
                                               float* __restrict__ qf,
                                               float* __restrict__ kf) {
    const float* QK = blockIdx.z ? Km : Qm;
    const float* Kmat = blockIdx.z ? Kk : Kq;
    float* feat = blockIdx.z ? kf : qf;
    const int h = blockIdx.y;
    const int l = blockIdx.x * 4 + threadIdx.y;
    const int f = threadIdx.x;
    __shared__ float qs[4][64];
    qs[threadIdx.y][f] = QK[l * 1024 + h * 64 + f];
    __syncthreads();
    const float* Kp = Kmat + h * 4096 + f;
    float acc = 0.f;
#pragma unroll 8
    for (int d = 0; d < 64; d++) acc += qs[threadIdx.y][d] * Kp[d * 64];
    float m1 = acc, m2 = -acc;
#pragma unroll
    for (int off = 32; off; off >>= 1) {
        m1 = fmaxf(m1, __shfl_xor(m1, off));
        m2 = fmaxf(m2, __shfl_xor(m2, off));
    }
    float e1 = expf(acc - m1), e2 = expf(-acc - m2);
    float s1 = e1, s2 = e2;
#pragma unroll
    for (int off = 32; off; off >>= 1) {
        s1 += __shfl_xor(s1, off);
        s2 += __shfl_xor(s2, off);
    }
    float* o = feat + (h * 1024 + l) * 128;
    o[f] = fmaxf(e1 / s1, 1e-12f);
    o[64 + f] = fmaxf(e2 / s2, 1e-12f);
}

// ---- Sc[h][c][d][f] = sum_{t in chunk} V[t][d]*kf[t][f]; ksum[h][c][f] = sum_t kf[t][f]
__global__ __launch_bounds__(256) void chunk_sums(const float* __restrict__ kf,
                                                  const float* __restrict__ V,
                                                  float* __restrict__ Sc,
                                                  float* __restrict__ ksum) {
    const int h = blockIdx.y, c = blockIdx.x, tid = threadIdx.x;
    const int l0 = c * CS;
    __shared__ float kfs[64][132];
    __shared__ float vs[64][68];
    const float4* k4 = (const float4*)(kf + (h * 1024 + l0) * 128);
    for (int i = tid; i < 2048; i += 256) {
        int r = i >> 5, c4 = i & 31;
        *(float4*)&kfs[r][c4 * 4] = k4[i];
    }
    for (int i = tid; i < 1024; i += 256) {
        int r = i >> 4, c4 = i & 15;
        *(float4*)&vs[r][c4 * 4] = *(const float4*)&V[(l0 + r) * 1024 + h * 64 + c4 * 4];
    }
    __syncthreads();
    const int d0 = (tid & 7) << 3, f0 = (tid >> 3) << 2;
    float acc[8][4] = {{0.f}};
    for (int t = 0; t < 64; t++) {
        float4 va = *(const float4*)&vs[t][d0];
        float4 vb = *(const float4*)&vs[t][d0 + 4];
        float4 kc = *(const float4*)&kfs[t][f0];
        float vv[8] = {va.x, va.y, va.z, va.w, vb.x, vb.y, vb.z, vb.w};
        float kv[4] = {kc.x, kc.y, kc.z, kc.w};
#pragma unroll
        for (int i = 0; i < 8; i++)
#pragma unroll
            for (int j = 0; j < 4; j++)
                acc[i][j] += vv[i] * kv[j];
    }
    float* o = Sc + (h * NC + c) * 8192;
#pragma unroll
    for (int i = 0; i < 8; i++)
#pragma unroll
        for (int j = 0; j < 4; j++)
            o[(d0 + i) * 128 + f0 + j] = acc[i][j];
    if (tid < 128) {
        float s = 0.f;
        for (int t = 0; t < 64; t++) s += kfs[t][tid];
        ksum[(h * NC + c) * 128 + tid] = s;
    }
}

__global__ __launch_bounds__(256) void prefix_scan(const float* __restrict__ Sc,
                                                   float* __restrict__ Sp,
                                                   const float* __restrict__ ksum,
                                                   float* __restrict__ kp) {
    const int h = blockIdx.x, eb = blockIdx.y, tid = threadIdx.x;
    for (int e = eb * 1024 + tid; e < (eb + 1) * 1024; e += 256) {
        float run = 0.f;
        for (int c = 0; c < NC; c++) {
            const int idx = (h * NC + c) * 8192 + e;
            Sp[idx] = run;
            run += Sc[idx];
        }
    }
    if (eb == 0 && tid < 128) {
        float run = 0.f;
        for (int c = 0; c < NC; c++) {
            const int idx = (h * NC + c) * 128 + tid;
            kp[idx] = run;
            run += ksum[idx];
        }
    }
}

__global__ __launch_bounds__(256) void chunk_out(const float* __restrict__ qf,
                                                 const float* __restrict__ kf,
                                                 const float* __restrict__ V,
                                                 const float* __restrict__ Sp,
                                                 const float* __restrict__ kp,
                                                 __hip_bfloat16* __restrict__ Y) {
    const int h = blockIdx.y, c = blockIdx.x, tid = threadIdx.x;
    const int l0 = c * CS;
    __shared__ float Qs[64][132];
    __shared__ float Ks[64][132];
    __shared__ float Vs[64][68];
    __shared__ float Am[64][68];
    __shared__ float kpre[128];
    __shared__ float invz[64];

    {
        const float4* q4 = (const float4*)(qf + (h * 1024 + l0) * 128);
        const float4* k4 = (const float4*)(kf + (h * 1024 + l0) * 128);
        for (int i = tid; i < 2048; i += 256) {
            int r = i >> 5, c4 = i & 31;
            *(float4*)&Qs[r][c4 * 4] = q4[i];
            *(float4*)&Ks[r][c4 * 4] = k4[i];
        }
        for (int i = tid; i < 1024; i += 256) {
            int r = i >> 4, c4 = i & 15;
            *(float4*)&Vs[r][c4 * 4] = *(const float4*)&V[(l0 + r) * 1024 + h * 64 + c4 * 4];
        }
        if (tid < 128) kpre[tid] = kp[(h * NC + c) * 128 + tid];
    }
    __syncthreads();

    const int t0 = (tid >> 4) << 2;
    const int s0 = (tid & 15) << 2;
    {
        float a[4][4] = {{0.f}};
        for (int f = 0; f < 128; f++) {
            float qv[4], kv[4];
#pragma unroll
            for (int i = 0; i < 4; i++) qv[i] = Qs[t0 + i][f];
#pragma unroll
            for (int j = 0; j < 4; j++) kv[j] = Ks[s0 + j][f];
#pragma unroll
            for (int i = 0; i < 4; i++)
#pragma unroll
                for (int j = 0; j < 4; j++)
                    a[i][j] += qv[i] * kv[j];
        }
#pragma unroll
        for (int i = 0; i < 4; i++)
#pragma unroll
            for (int j = 0; j < 4; j++)
                Am[t0 + i][s0 + j] = (s0 + j <= t0 + i) ? a[i][j] : 0.0f;
    }
    __syncthreads();
    {
        const float4* s4 = (const float4*)(Sp + (h * NC + c) * 8192);
        for (int i = tid; i < 2048; i += 256) {
            int r = i >> 5, c4 = i & 31;
            *(float4*)&Ks[r][c4 * 4] = s4[i];
        }
        if (tid < 64) {
            const int t = tid;
            float z = 1e-12f;
            for (int s = 0; s < 64; s++) z += Am[t][s];
            for (int f = 0; f < 128; f++) z += Qs[t][f] * kpre[f];
            invz[t] = 1.0f / z;
        }
    }
    __syncthreads();
    {
        const int d0 = s0;
        float o[4][4] = {{0.f}};
        for (int s = 0; s < 64; s++) {
            float av[4], vv[4];
#pragma unroll
            for (int i = 0; i < 4; i++) av[i] = Am[t0 + i][s];
#pragma unroll
            for (int j = 0; j < 4; j++) vv[j] = Vs[s][d0 + j];
#pragma unroll
            for (int i = 0; i < 4; i++)
#pragma unroll
                for (int j = 0; j < 4; j++)
                    o[i][j] += av[i] * vv[j];
        }
        for (int f = 0; f < 128; f++) {
            float qv[4], sv[4];
#pragma unroll
            for (int i = 0; i < 4; i++) qv[i] = Qs[t0 + i][f];
#pragma unroll
            for (int j = 0; j < 4; j++) sv[j] = Ks[d0 + j][f];
#pragma unroll
            for (int i = 0; i < 4; i++)
#pragma unroll
                for (int j = 0; j < 4; j++)
                    o[i][j] += qv[i] * sv[j];
        }
#pragma unroll
        for (int i = 0; i < 4; i++)
#pragma unroll
            for (int j = 0; j < 4; j++)
                Y[(size_t)(l0 + t0 + i) * 1024 + h * 64 + d0 + j] =
                    __float2bfloat16(o[i][j] * invz[t0 + i]);
    }
}

extern "C" void kernel_launch(void* const* d_in, const int* in_sizes, int n_in,
                              void* d_out, int out_size, void* d_ws, size_t ws_size,
                              hipStream_t stream) {
    const float* x  = (const float*)d_in[0];
    const float* Wq = (const float*)d_in[1];
    const float* Wk = (const float*)d_in[2];
    const float* Wv = (const float*)d_in[3];
    const float* Wo = (const float*)d_in[4];
    const float* Kq = (const float*)d_in[5];
    const float* Kk = (const float*)d_in[6];
    float* out = (float*)d_out;
    float* ws = (float*)d_ws;

    const size_t M1 = 1024 * 1024;
    // f32 regions
    float* V   = ws;               // 0..1M
    float* qf  = ws + 1 * M1;      // 1..3M
    float* kfb = ws + 3 * M1;      // 3..5M
    float* Q   = ws + 5 * M1;      // 5..6M (dead after featmap)
    float* K   = ws + 6 * M1;      // 6..7M (dead after featmap)
    float* Sc  = ws + 5 * M1;      // 5..7M (aliases Q,K)
    float* Sp  = ws + 7 * M1;      // 7..9M (aliases xb+W^T after QKV gemm)
    float* ksum = ws + 10 * M1;            // 32K
    float* kp   = ws + 10 * M1 + 32768;    // 32K
    // bf16 regions (within f32 slot space)
    __hip_bfloat16* xb  = (__hip_bfloat16*)(ws + 7 * M1);            // 7..7.5M (dead after gemm)
    __hip_bfloat16* Wqt = (__hip_bfloat16*)(ws + 7 * M1 + M1 / 2);   // 7.5..8M
    __hip_bfloat16* Wkt = (__hip_bfloat16*)(ws + 8 * M1);            // 8..8.5M
    __hip_bfloat16* Wvt = (__hip_bfloat16*)(ws + 8 * M1 + M1 / 2);   // 8.5..9M
    __hip_bfloat16* Wot = (__hip_bfloat16*)(ws + 9 * M1);            // 9..9.5M (live till end)
    __hip_bfloat16* Yb  = (__hip_bfloat16*)(ws + 9 * M1 + M1 / 2);   // 9.5..10M
    if (ws_size < (10 * M1 + 65536) * sizeof(float)) return;

    wt_convert<<<dim3(32, 32, 4), dim3(32, 8), 0, stream>>>(Wq, Wk, Wv, Wo, Wqt, Wkt, Wvt, Wot);
    x_convert<<<1024, 256, 0, stream>>>(x, xb);
    gemm_bt_bf16<3><<<dim3(48, 16), 256, 0, stream>>>(xb, Wqt, Wkt, Wvt, Q, K, V);
    featmap<<<dim3(256, 16, 2), dim3(64, 4), 0, stream>>>(Q, K, Kq, Kk, qf, kfb);
    chunk_sums<<<dim3(NC, NH), 256, 0, stream>>>(kfb, V, Sc, ksum);
    prefix_scan<<<dim3(NH, 8), 256, 0, stream>>>(Sc, Sp, ksum, kp);
    chunk_out<<<dim3(NC, NH), 256, 0, stream>>>(qf, kfb, V, Sp, kp, Yb);
    gemm_bt_bf16<1><<<dim3(16, 16), 256, 0, stream>>>(Yb, Wot, nullptr, nullptr, out, nullptr, nullptr);
}

// Round 3
// 74.765 us; speedup vs baseline: 3.8398x; 1.3192x over previous
//
#include <hip/hip_runtime.h>
#include <hip/hip_bf16.h>

// Hedgehog linear attention, B=1, L=1024, D=1024, H=16, HD=64, FD=64.
// Round 3: MFMA everywhere. bf16 intermediates for feats/V^T/Sp/Am/Y.
//  0) wt_convert (W^T bf16), x_convert, kmat_convert (Kq/Kk -> bf16 transposed)
//  1) gemm_bt_bf16<3>: Q,K,V f32 = x @ W           (MFMA, 64x64 tiles)
//  2) vt_convert: V -> V^T bf16
//  3) featmap_mfma: qf/kf bf16 (and kf^T bf16)      (MFMA + wave softmax)
//  4) chunk_sums_mfma: Sc f32 = V^T @ kf            (MFMA)
//  5) prefix_scan: Sp bf16, kp f32
//  6) chunk_out_mfma: Y bf16 = ((QK^T masked)V + Qf Sp^T) / z   (MFMA)
//  7) gemm_bt_bf16<1>: out = Y @ Wo

#define NH 16
#define NC 16

using short8 = __attribute__((ext_vector_type(8))) short;
using f32x4  = __attribute__((ext_vector_type(4))) float;
typedef const __attribute__((address_space(1))) char* gptr1;
typedef __attribute__((address_space(3))) char* lptr3;

static __device__ __forceinline__ unsigned short bf16bits(float x) {
    __hip_bfloat16 h = __float2bfloat16(x);
    return __builtin_bit_cast(unsigned short, h);
}
static __device__ __forceinline__ float b2f(unsigned short u) {
    return __builtin_bit_cast(float, (unsigned int)u << 16);
}
#define SWZ(row, cb) ((cb) ^ (((row) & 7) << 4))

// frag load: 8 contiguous bf16 of row `row` at element offset `kelem`, swizzled LDS
template<int RS>
static __device__ __forceinline__ short8 ldfrag(const char* buf, int row, int kelem) {
    return *(const short8*)(buf + row * RS + SWZ(row, kelem * 2));
}

// ---- weight transpose + convert: src f32 (K x N) -> dst bf16 (N x K)
__global__ __launch_bounds__(256) void wt_convert(const float* __restrict__ s0,
                                                  const float* __restrict__ s1,
                                                  const float* __restrict__ s2,
                                                  const float* __restrict__ s3,
                                                  __hip_bfloat16* __restrict__ d0,
                                                  __hip_bfloat16* __restrict__ d1,
                                                  __hip_bfloat16* __restrict__ d2,
                                                  __hip_bfloat16* __restrict__ d3) {
    const float* src = (blockIdx.z == 0) ? s0 : (blockIdx.z == 1) ? s1 : (blockIdx.z == 2) ? s2 : s3;
    __hip_bfloat16* dst = (blockIdx.z == 0) ? d0 : (blockIdx.z == 1) ? d1 : (blockIdx.z == 2) ? d2 : d3;
    __shared__ float tile[32][33];
    const int bx = blockIdx.x * 32, by = blockIdx.y * 32;
    const int tx = threadIdx.x, ty = threadIdx.y;
#pragma unroll
    for (int i = 0; i < 32; i += 8)
        tile[ty + i][tx] = src[(by + ty + i) * 1024 + bx + tx];
    __syncthreads();
#pragma unroll
    for (int i = 0; i < 32; i += 8)
        dst[(size_t)(bx + ty + i) * 1024 + by + tx] = __float2bfloat16(tile[tx][ty + i]);
}

// ---- V f32 -> V^T bf16 (1024x1024 transpose)
__global__ __launch_bounds__(256) void vt_convert(const float* __restrict__ V,
                                                  __hip_bfloat16* __restrict__ VT) {
    __shared__ float tile[32][33];
    const int bx = blockIdx.x * 32, by = blockIdx.y * 32;
    const int tx = threadIdx.x, ty = threadIdx.y;
#pragma unroll
    for (int i = 0; i < 32; i += 8)
        tile[ty + i][tx] = V[(by + ty + i) * 1024 + bx + tx];
    __syncthreads();
#pragma unroll
    for (int i = 0; i < 32; i += 8)
        VT[(size_t)(bx + ty + i) * 1024 + by + tx] = __float2bfloat16(tile[tx][ty + i]);
}

// ---- x f32 -> bf16
__global__ __launch_bounds__(256) void x_convert(const float* __restrict__ s,
                                                 __hip_bfloat16* __restrict__ d) {
    const int i = (blockIdx.x * 256 + threadIdx.x) * 4;
    float4 v = *(const float4*)(s + i);
    ushort4 o;
    o.x = bf16bits(v.x); o.y = bf16bits(v.y); o.z = bf16bits(v.z); o.w = bf16bits(v.w);
    *(ushort4*)((unsigned short*)d + i) = o;
}

// ---- Kq/Kk f32 [h][d][f] -> bf16 [h][f][d] (per-head 64x64 transpose)
__global__ __launch_bounds__(256) void kmat_convert(const float* __restrict__ Kq,
                                                    const float* __restrict__ Kk,
                                                    __hip_bfloat16* __restrict__ KqT,
                                                    __hip_bfloat16* __restrict__ KkT) {
    const int h = blockIdx.x & 15;
    const float* S = (blockIdx.x >> 4) ? Kk : Kq;
    __hip_bfloat16* D = (blockIdx.x >> 4) ? KkT : KqT;
    __shared__ float t[64][65];
    const int tid = threadIdx.x;
#pragma unroll
    for (int j = 0; j < 16; j++) {
        int e = tid + j * 256, r = e >> 6, c = e & 63;
        t[r][c] = S[h * 4096 + r * 64 + c];
    }
    __syncthreads();
#pragma unroll
    for (int j = 0; j < 16; j++) {
        int e = tid + j * 256, r = e >> 6, c = e & 63;
        D[h * 4096 + r * 64 + c] = __float2bfloat16(t[c][r]);
    }
}

// ---- bf16 MFMA GEMM, A (M x K), B^T (N x K), C f32 (M x N). (validated r1)
template<int NMAT>
__global__ __launch_bounds__(256) void gemm_bt_bf16(const __hip_bfloat16* __restrict__ A,
                                                    const __hip_bfloat16* __restrict__ B0,
                                                    const __hip_bfloat16* __restrict__ B1,
                                                    const __hip_bfloat16* __restrict__ B2,
                                                    float* __restrict__ C0,
                                                    float* __restrict__ C1,
                                                    float* __restrict__ C2) {
    __shared__ __align__(16) char Abuf[64 * 128];
    __shared__ __align__(16) char Bbuf[64 * 128];
    const int tid = threadIdx.x;
    const int bm = blockIdx.y * 64;
    int nb = blockIdx.x;
    const __hip_bfloat16* B = B0;
    float* C = C0;
    if (NMAT == 3) {
        const int which = nb >> 4;
        nb &= 15;
        if (which == 1) { B = B1; C = C1; }
        else if (which == 2) { B = B2; C = C2; }
    }
    const int bn = nb * 64;
    const int srow = tid >> 3;
    const int scol0 = (tid & 7) * 16;
    const int wid = tid >> 6, lane = tid & 63;
    const int g = lane >> 4, r16 = lane & 15;
    const int wr = wid >> 1, wc = wid & 1;
    const char* Ab = (const char*)A;
    const char* Bb = (const char*)B;
    f32x4 acc[2][2] = {};
    for (int kt = 0; kt < 16; kt++) {
        const int kbyte = kt * 128;
#pragma unroll
        for (int hh = 0; hh < 2; hh++) {
            const int row = hh * 32 + srow;
            const int sc = scol0 ^ ((row & 7) << 4);
            __builtin_amdgcn_global_load_lds((gptr1)(Ab + (size_t)(bm + row) * 2048 + kbyte + sc),
                                             (lptr3)(Abuf + hh * 4096 + wid * 1024), 16, 0, 0);
            __builtin_amdgcn_global_load_lds((gptr1)(Bb + (size_t)(bn + row) * 2048 + kbyte + sc),
                                             (lptr3)(Bbuf + hh * 4096 + wid * 1024), 16, 0, 0);
        }
        __syncthreads();
#pragma unroll
        for (int ks = 0; ks < 2; ks++) {
            short8 af[2], bfr[2];
#pragma unroll
            for (int m = 0; m < 2; m++)
                af[m] = ldfrag<128>(Abuf, wr * 32 + m * 16 + r16, ks * 32 + g * 8);
#pragma unroll
            for (int n = 0; n < 2; n++)
                bfr[n] = ldfrag<128>(Bbuf, wc * 32 + n * 16 + r16, ks * 32 + g * 8);
#pragma unroll
            for (int m = 0; m < 2; m++)
#pragma unroll
                for (int n = 0; n < 2; n++)
                    acc[m][n] = __builtin_amdgcn_mfma_f32_16x16x32_bf16(af[m], bfr[n], acc[m][n], 0, 0, 0);
        }
        __syncthreads();
    }
#pragma unroll
    for (int m = 0; m < 2; m++)
#pragma unroll
        for (int n = 0; n < 2; n++)
#pragma unroll
            for (int i = 0; i < 4; i++) {
                const int row = bm + wr * 32 + m * 16 + g * 4 + i;
                const int col = bn + wc * 32 + n * 16 + r16;
                C[(size_t)row * 1024 + col] = acc[m][n][i];
            }
}

// ---- featmap: per (ltile, h, side): f = Xtile @ KT^T; feats = [softmax(f), softmax(-f)] clamped
__global__ __launch_bounds__(256) void featmap_mfma(const float* __restrict__ Q,
                                                    const float* __restrict__ K,
                                                    const __hip_bfloat16* __restrict__ KqT,
                                                    const __hip_bfloat16* __restrict__ KkT,
                                                    __hip_bfloat16* __restrict__ qf,
                                                    __hip_bfloat16* __restrict__ kf,
                                                    __hip_bfloat16* __restrict__ kfT) {
    const bool kside = (blockIdx.z != 0);
    const float* X = kside ? K : Q;
    const __hip_bfloat16* KT = kside ? KkT : KqT;
    __hip_bfloat16* feat = kside ? kf : qf;
    const int h = blockIdx.y, l0 = blockIdx.x * 64;
    __shared__ __align__(16) char Xs[64 * 128];   // bf16 [l][d], swz
    __shared__ __align__(16) char Ks[64 * 128];   // bf16 [f][d], swz
    __shared__ __align__(16) char ft[128 * 128];  // bf16 [col][l], swz (k-side)
    const int tid = threadIdx.x, lane = tid & 63, wid = tid >> 6;
    const int r16 = lane & 15, g = lane >> 4;

    // stage X (f32 -> bf16, swizzled)
#pragma unroll
    for (int j = 0; j < 4; j++) {
        int e = tid + j * 256;              // float4 index
        int row = e >> 4, c4 = e & 15;
        float4 v = *(const float4*)&X[(size_t)(l0 + row) * 1024 + h * 64 + c4 * 4];
        ushort4 o;
        o.x = bf16bits(v.x); o.y = bf16bits(v.y); o.z = bf16bits(v.z); o.w = bf16bits(v.w);
        *(ushort4*)(Xs + row * 128 + SWZ(row, c4 * 8)) = o;
    }
    // stage KT via global_load_lds (pre-swizzled source)
#pragma unroll
    for (int it = 0; it < 2; it++) {
        int off = it * 4096 + wid * 1024 + lane * 16;
        int row = off >> 7, cb = off & 127;
        __builtin_amdgcn_global_load_lds((gptr1)((const char*)KT + (size_t)(h * 64 + row) * 128 + SWZ(row, cb)),
                                         (lptr3)(Ks + it * 4096 + wid * 1024), 16, 0, 0);
    }
    __syncthreads();

    f32x4 acc[4] = {};
#pragma unroll
    for (int ks = 0; ks < 2; ks++) {
        short8 a = ldfrag<128>(Xs, wid * 16 + r16, ks * 32 + g * 8);
#pragma unroll
        for (int n = 0; n < 4; n++) {
            short8 b = ldfrag<128>(Ks, n * 16 + r16, ks * 32 + g * 8);
            acc[n] = __builtin_amdgcn_mfma_f32_16x16x32_bf16(a, b, acc[n], 0, 0, 0);
        }
    }

#pragma unroll
    for (int i = 0; i < 4; i++) {
        const int row = wid * 16 + g * 4 + i;   // l within tile
        float m1 = acc[0][i], m2 = -acc[0][i];
#pragma unroll
        for (int n = 1; n < 4; n++) {
            m1 = fmaxf(m1, acc[n][i]);
            m2 = fmaxf(m2, -acc[n][i]);
        }
#pragma unroll
        for (int off = 8; off; off >>= 1) {
            m1 = fmaxf(m1, __shfl_xor(m1, off));
            m2 = fmaxf(m2, __shfl_xor(m2, off));
        }
        float e1[4], e2[4], s1 = 0.f, s2 = 0.f;
#pragma unroll
        for (int n = 0; n < 4; n++) {
            e1[n] = __expf(acc[n][i] - m1);  s1 += e1[n];
            e2[n] = __expf(-acc[n][i] - m2); s2 += e2[n];
        }
#pragma unroll
        for (int off = 8; off; off >>= 1) {
            s1 += __shfl_xor(s1, off);
            s2 += __shfl_xor(s2, off);
        }
        const float i1 = 1.f / s1, i2 = 1.f / s2;
        __hip_bfloat16* fo = feat + ((size_t)(h * 1024 + l0 + row)) * 128;
#pragma unroll
        for (int n = 0; n < 4; n++) {
            const int col = n * 16 + r16;
            unsigned short v1 = bf16bits(fmaxf(e1[n] * i1, 1e-12f));
            unsigned short v2 = bf16bits(fmaxf(e2[n] * i2, 1e-12f));
            *(unsigned short*)(fo + col) = v1;
            *(unsigned short*)(fo + col + 64) = v2;
            if (kside) {
                *(unsigned short*)(ft + col * 128 + SWZ(col, row * 2)) = v1;
                *(unsigned short*)(ft + (col + 64) * 128 + SWZ(col + 64, row * 2)) = v2;
            }
        }
    }
    if (kside) {
        __syncthreads();
        // coalesced kfT write: [h][128 f][1024 l] slice cols l0..l0+63
#pragma unroll
        for (int j = 0; j < 4; j++) {
            int off = (tid + j * 256) * 16;
            int row = off >> 7, cb = off & 127;
            short8 v = *(const short8*)(ft + row * 128 + SWZ(row, cb));
            *(short8*)((char*)kfT + ((size_t)(h * 128 + row) * 1024 + l0) * 2 + cb) = v;
        }
    }
}

// ---- Sc[h][c][d][f] f32 = V^T @ kf ; ksum[h][c][f]
__global__ __launch_bounds__(256) void chunk_sums_mfma(const __hip_bfloat16* __restrict__ kfT,
                                                       const __hip_bfloat16* __restrict__ VT,
                                                       float* __restrict__ Sc,
                                                       float* __restrict__ ksum) {
    const int h = blockIdx.y, c = blockIdx.x, l0 = c * 64;
    __shared__ __align__(16) char VTs[64 * 128];    // [d][t]
    __shared__ __align__(16) char KTs[128 * 128];   // [f][t]
    const int tid = threadIdx.x, lane = tid & 63, wid = tid >> 6;
    const int r16 = lane & 15, g = lane >> 4;
#pragma unroll
    for (int it = 0; it < 2; it++) {
        int off = it * 4096 + wid * 1024 + lane * 16;
        int row = off >> 7, cb = off & 127;
        __builtin_amdgcn_global_load_lds((gptr1)((const char*)VT + ((size_t)(h * 64 + row) * 1024 + l0) * 2 + SWZ(row, cb)),
                                         (lptr3)(VTs + it * 4096 + wid * 1024), 16, 0, 0);
    }
#pragma unroll
    for (int it = 0; it < 4; it++) {
        int off = it * 4096 + wid * 1024 + lane * 16;
        int row = off >> 7, cb = off & 127;
        __builtin_amdgcn_global_load_lds((gptr1)((const char*)kfT + ((size_t)(h * 128 + row) * 1024 + l0) * 2 + SWZ(row, cb)),
                                         (lptr3)(KTs + it * 4096 + wid * 1024), 16, 0, 0);
    }
    __syncthreads();
    f32x4 acc[8] = {};
#pragma unroll
    for (int ks = 0; ks < 2; ks++) {
        short8 a = ldfrag<128>(VTs, wid * 16 + r16, ks * 32 + g * 8);
#pragma unroll
        for (int n = 0; n < 8; n++) {
            short8 b = ldfrag<128>(KTs, n * 16 + r16, ks * 32 + g * 8);
            acc[n] = __builtin_amdgcn_mfma_f32_16x16x32_bf16(a, b, acc[n], 0, 0, 0);
        }
    }
    float* o = Sc + (size_t)(h * NC + c) * 8192;
#pragma unroll
    for (int n = 0; n < 8; n++)
#pragma unroll
        for (int i = 0; i < 4; i++)
            o[(wid * 16 + g * 4 + i) * 128 + n * 16 + r16] = acc[n][i];
    if (tid < 128) {
        float s = 0.f;
#pragma unroll 8
        for (int t = 0; t < 64; t++)
            s += b2f(*(const unsigned short*)(KTs + tid * 128 + SWZ(tid, t * 2)));
        ksum[(size_t)(h * NC + c) * 128 + tid] = s;
    }
}

// ---- exclusive prefix over chunks: Sp bf16, kp f32
__global__ __launch_bounds__(256) void prefix_scan(const float* __restrict__ Sc,
                                                   __hip_bfloat16* __restrict__ Sp,
                                                   const float* __restrict__ ksum,
                                                   float* __restrict__ kp) {
    const int h = blockIdx.x, eb = blockIdx.y, tid = threadIdx.x;
#pragma unroll
    for (int j = 0; j < 4; j++) {
        const int e = eb * 1024 + tid + j * 256;
        float run = 0.f;
        for (int c = 0; c < NC; c++) {
            const size_t idx = (size_t)(h * NC + c) * 8192 + e;
            Sp[idx] = __float2bfloat16(run);
            run += Sc[idx];
        }
    }
    if (eb == 0 && tid < 128) {
        float run = 0.f;
        for (int c = 0; c < NC; c++) {
            const size_t idx = (size_t)(h * NC + c) * 128 + tid;
            kp[idx] = run;
            run += ksum[idx];
        }
    }
}

// ---- chunk_out: Y = ((Qf Kf^T masked) V + Qf Sp^T) / z, bf16 out
__global__ __launch_bounds__(256) void chunk_out_mfma(const __hip_bfloat16* __restrict__ qf,
                                                      const __hip_bfloat16* __restrict__ kf,
                                                      const __hip_bfloat16* __restrict__ VT,
                                                      const __hip_bfloat16* __restrict__ Sp,
                                                      const float* __restrict__ kp,
                                                      __hip_bfloat16* __restrict__ Y) {
    const int h = blockIdx.y, c = blockIdx.x, l0 = c * 64;
    __shared__ __align__(16) char QF[64 * 256];   // [l][128f]
    __shared__ __align__(16) char KF[64 * 256];   // [s][128f]
    __shared__ __align__(16) char SP[64 * 256];   // [d][128f]
    __shared__ __align__(16) char VTs[64 * 128];  // [d][64s]
    __shared__ __align__(16) char AM[64 * 128];   // [l][64s]
    __shared__ float zi[64];
    __shared__ float invz[64];
    const int tid = threadIdx.x, lane = tid & 63, wid = tid >> 6;
    const int r16 = lane & 15, g = lane >> 4;

#pragma unroll
    for (int it = 0; it < 4; it++) {
        int off = it * 4096 + wid * 1024 + lane * 16;
        int row = off >> 8, cb = off & 255;
        int sw = SWZ(row, cb);
        __builtin_amdgcn_global_load_lds((gptr1)((const char*)qf + ((size_t)(h * 1024 + l0 + row)) * 256 + sw),
                                         (lptr3)(QF + it * 4096 + wid * 1024), 16, 0, 0);
        __builtin_amdgcn_global_load_lds((gptr1)((const char*)kf + ((size_t)(h * 1024 + l0 + row)) * 256 + sw),
                                         (lptr3)(KF + it * 4096 + wid * 1024), 16, 0, 0);
        __builtin_amdgcn_global_load_lds((gptr1)((const char*)Sp + ((size_t)((h * NC + c) * 64 + row)) * 256 + sw),
                                         (lptr3)(SP + it * 4096 + wid * 1024), 16, 0, 0);
    }
#pragma unroll
    for (int it = 0; it < 2; it++) {
        int off = it * 4096 + wid * 1024 + lane * 16;
        int row = off >> 7, cb = off & 127;
        __builtin_amdgcn_global_load_lds((gptr1)((const char*)VT + ((size_t)(h * 64 + row) * 1024 + l0) * 2 + SWZ(row, cb)),
                                         (lptr3)(VTs + it * 4096 + wid * 1024), 16, 0, 0);
    }
    __syncthreads();

    // QK^T over K=128
    f32x4 a4[4] = {};
#pragma unroll
    for (int ks = 0; ks < 4; ks++) {
        short8 a = ldfrag<256>(QF, wid * 16 + r16, ks * 32 + g * 8);
#pragma unroll
        for (int n = 0; n < 4; n++) {
            short8 b = ldfrag<256>(KF, n * 16 + r16, ks * 32 + g * 8);
            a4[n] = __builtin_amdgcn_mfma_f32_16x16x32_bf16(a, b, a4[n], 0, 0, 0);
        }
    }
    // mask + row-sum + Am write
    const int rowl = wid * 16 + g * 4;
#pragma unroll
    for (int i = 0; i < 4; i++) {
        float r = 0.f;
#pragma unroll
        for (int n = 0; n < 4; n++) {
            const int col = n * 16 + r16;
            float v = (col <= rowl + i) ? a4[n][i] : 0.f;
            a4[n][i] = v;
            r += v;
        }
#pragma unroll
        for (int off = 8; off; off >>= 1) r += __shfl_xor(r, off);
        if (r16 == 0) zi[rowl + i] = r;
#pragma unroll
        for (int n = 0; n < 4; n++)
            *(unsigned short*)(AM + (rowl + i) * 128 + SWZ(rowl + i, (n * 16 + r16) * 2)) = bf16bits(a4[n][i]);
    }
    __syncthreads();

    // z = zi + qf . kp  (threads 0..63, one row each)
    if (tid < 64) {
        float z = zi[tid] + 1e-12f;
        const float* kpp = kp + (size_t)(h * NC + c) * 128;
#pragma unroll 8
        for (int f = 0; f < 128; f++)
            z += b2f(*(const unsigned short*)(QF + tid * 256 + SWZ(tid, f * 2))) * kpp[f];
        invz[tid] = 1.f / z;
    }

    // O = Am @ V + Qf @ Sp^T
    f32x4 o4[4] = {};
#pragma unroll
    for (int ks = 0; ks < 2; ks++) {
        short8 a = ldfrag<128>(AM, wid * 16 + r16, ks * 32 + g * 8);
#pragma unroll
        for (int n = 0; n < 4; n++) {
            short8 b = ldfrag<128>(VTs, n * 16 + r16, ks * 32 + g * 8);
            o4[n] = __builtin_amdgcn_mfma_f32_16x16x32_bf16(a, b, o4[n], 0, 0, 0);
        }
    }
#pragma unroll
    for (int ks = 0; ks < 4; ks++) {
        short8 a = ldfrag<256>(QF, wid * 16 + r16, ks * 32 + g * 8);
#pragma unroll
        for (int n = 0; n < 4; n++) {
            short8 b = ldfrag<256>(SP, n * 16 + r16, ks * 32 + g * 8);
            o4[n] = __builtin_amdgcn_mfma_f32_16x16x32_bf16(a, b, o4[n], 0, 0, 0);
        }
    }
    __syncthreads();
#pragma unroll
    for (int n = 0; n < 4; n++)
#pragma unroll
        for (int i = 0; i < 4; i++) {
            const int row = rowl + i, col = n * 16 + r16;
            Y[((size_t)(l0 + row)) * 1024 + h * 64 + col] = __float2bfloat16(o4[n][i] * invz[row]);
        }
}

extern "C" void kernel_launch(void* const* d_in, const int* in_sizes, int n_in,
                              void* d_out, int out_size, void* d_ws, size_t ws_size,
                              hipStream_t stream) {
    const float* x  = (const float*)d_in[0];
    const float* Wq = (const float*)d_in[1];
    const float* Wk = (const float*)d_in[2];
    const float* Wv = (const float*)d_in[3];
    const float* Wo = (const float*)d_in[4];
    const float* Kq = (const float*)d_in[5];
    const float* Kk = (const float*)d_in[6];
    float* out = (float*)d_out;
    float* ws = (float*)d_ws;

    const size_t M1 = 1024 * 1024;
    if (ws_size < 13 * M1 * sizeof(float)) return;

    float* Q    = ws;                         // [0, 1M)
    float* K    = ws + 1 * M1;                // [1M, 2M)
    float* V    = ws + 2 * M1;                // [2M, 3M)
    float* Sc   = ws + 3 * M1;                // [3M, 5M)
    float* ksum = ws + 5 * M1;                // 32K
    float* kp   = ws + 5 * M1 + 32768;        // 32K
    __hip_bfloat16* xb   = (__hip_bfloat16*)(ws + 5 * M1 + M1 / 4);   // 1M bf16
    __hip_bfloat16* Wqt  = (__hip_bfloat16*)(ws + 5 * M1 + 3 * M1 / 4);
    __hip_bfloat16* Wkt  = (__hip_bfloat16*)(ws + 6 * M1 + M1 / 4);
    __hip_bfloat16* Wvt  = (__hip_bfloat16*)(ws + 6 * M1 + 3 * M1 / 4);
    __hip_bfloat16* Wot  = (__hip_bfloat16*)(ws + 7 * M1 + M1 / 4);
    __hip_bfloat16* KqT  = (__hip_bfloat16*)(ws + 7 * M1 + 3 * M1 / 4);  // 64K bf16
    __hip_bfloat16* KkT  = (__hip_bfloat16*)(ws + 7 * M1 + 3 * M1 / 4 + 32768);
    __hip_bfloat16* VT   = (__hip_bfloat16*)(ws + 8 * M1);            // 1M bf16
    __hip_bfloat16* qfb  = (__hip_bfloat16*)(ws + 8 * M1 + M1 / 2);   // 2M bf16
    __hip_bfloat16* kfb  = (__hip_bfloat16*)(ws + 9 * M1 + M1 / 2);   // 2M bf16
    __hip_bfloat16* kfT  = (__hip_bfloat16*)(ws + 10 * M1 + M1 / 2);  // 2M bf16
    __hip_bfloat16* Spb  = (__hip_bfloat16*)(ws + 11 * M1 + M1 / 2);  // 2M bf16
    __hip_bfloat16* Yb   = (__hip_bfloat16*)(ws + 12 * M1 + M1 / 2);  // 1M bf16

    wt_convert<<<dim3(32, 32, 4), dim3(32, 8), 0, stream>>>(Wq, Wk, Wv, Wo, Wqt, Wkt, Wvt, Wot);
    x_convert<<<1024, 256, 0, stream>>>(x, xb);
    kmat_convert<<<32, 256, 0, stream>>>(Kq, Kk, KqT, KkT);
    gemm_bt_bf16<3><<<dim3(48, 16), 256, 0, stream>>>(xb, Wqt, Wkt, Wvt, Q, K, V);
    vt_convert<<<dim3(32, 32), dim3(32, 8), 0, stream>>>(V, VT);
    featmap_mfma<<<dim3(16, 16, 2), 256, 0, stream>>>(Q, K, KqT, KkT, qfb, kfb, kfT);
    chunk_sums_mfma<<<dim3(NC, NH), 256, 0, stream>>>(kfT, VT, Sc, ksum);
    prefix_scan<<<dim3(NH, 8), 256, 0, stream>>>(Sc, Spb, ksum, kp);
    chunk_out_mfma<<<dim3(NC, NH), 256, 0, stream>>>(qfb, kfb, VT, Spb, kp, Yb);
    gemm_bt_bf16<1><<<dim3(16, 16), 256, 0, stream>>>(Yb, Wot, nullptr, nullptr, out, nullptr, nullptr);
}

// Round 4
// 71.435 us; speedup vs baseline: 4.0188x; 1.0466x over previous
//
#include <hip/hip_runtime.h>
#include <hip/hip_bf16.h>

// Hedgehog linear attention, B=1, L=1024, D=1024, H=16, HD=64, FD=64.
// Round 4: 128x64-tile QKV GEMM emitting bf16 Q/K + transposed V^T directly;
// bf16 Sc; fused prep kernel; 7 launches total.
//  1) prep: W^T bf16 (x4), x bf16, Kq/Kk^T bf16
//  2) qkv_gemm128: Qb,Kb bf16; VT bf16 (transposed epilogue)
//  3) featmap_mfma: qf/kf bf16 + kfT                (MFMA + wave softmax)
//  4) chunk_sums_mfma: Sc bf16 = V^T @ kf, ksum f32 (MFMA)
//  5) prefix_scan: Sp bf16 (f32 accum), kp f32
//  6) chunk_out_mfma: Y bf16                        (MFMA)
//  7) gemm_bt_bf16<1>: out f32 = Y @ Wo

#define NH 16
#define NC 16

using short8 = __attribute__((ext_vector_type(8))) short;
using f32x4  = __attribute__((ext_vector_type(4))) float;
typedef const __attribute__((address_space(1))) char* gptr1;
typedef __attribute__((address_space(3))) char* lptr3;

static __device__ __forceinline__ unsigned short bf16bits(float x) {
    __hip_bfloat16 h = __float2bfloat16(x);
    return __builtin_bit_cast(unsigned short, h);
}
static __device__ __forceinline__ float b2f(unsigned short u) {
    return __builtin_bit_cast(float, (unsigned int)u << 16);
}
#define SWZ(row, cb) ((cb) ^ (((row) & 7) << 4))

template<int RS>
static __device__ __forceinline__ short8 ldfrag(const char* buf, int row, int kelem) {
    return *(const short8*)(buf + row * RS + SWZ(row, kelem * 2));
}

// ---- fused prep: z<4 weight transpose+convert; z==4 x convert; z==5 kmat transpose
__global__ __launch_bounds__(256) void prep(const float* __restrict__ x,
                                            const float* __restrict__ w0,
                                            const float* __restrict__ w1,
                                            const float* __restrict__ w2,
                                            const float* __restrict__ w3,
                                            const float* __restrict__ Kq,
                                            const float* __restrict__ Kk,
                                            __hip_bfloat16* __restrict__ xb,
                                            __hip_bfloat16* __restrict__ d0,
                                            __hip_bfloat16* __restrict__ d1,
                                            __hip_bfloat16* __restrict__ d2,
                                            __hip_bfloat16* __restrict__ d3,
                                            __hip_bfloat16* __restrict__ KqT,
                                            __hip_bfloat16* __restrict__ KkT) {
    const int z = blockIdx.z;
    const int tx = threadIdx.x, ty = threadIdx.y;
    const int tid = ty * 32 + tx;
    if (z < 4) {
        const float* src = (z == 0) ? w0 : (z == 1) ? w1 : (z == 2) ? w2 : w3;
        __hip_bfloat16* dst = (z == 0) ? d0 : (z == 1) ? d1 : (z == 2) ? d2 : d3;
        __shared__ float tile[32][33];
        const int bx = blockIdx.x * 32, by = blockIdx.y * 32;
#pragma unroll
        for (int i = 0; i < 32; i += 8)
            tile[ty + i][tx] = src[(by + ty + i) * 1024 + bx + tx];
        __syncthreads();
#pragma unroll
        for (int i = 0; i < 32; i += 8)
            dst[(size_t)(bx + ty + i) * 1024 + by + tx] = __float2bfloat16(tile[tx][ty + i]);
    } else if (z == 4) {
        const int blk = blockIdx.y * 32 + blockIdx.x;
        const int i = (blk * 256 + tid) * 4;
        float4 v = *(const float4*)(x + i);
        ushort4 o;
        o.x = bf16bits(v.x); o.y = bf16bits(v.y); o.z = bf16bits(v.z); o.w = bf16bits(v.w);
        *(ushort4*)((unsigned short*)xb + i) = o;
    } else {
        if (blockIdx.y != 0 || blockIdx.x >= 32) return;
        const int h = blockIdx.x & 15;
        const float* S = (blockIdx.x >> 4) ? Kk : Kq;
        __hip_bfloat16* D = (blockIdx.x >> 4) ? KkT : KqT;
        __shared__ float t[64][65];
#pragma unroll
        for (int j = 0; j < 16; j++) {
            int e = tid + j * 256, r = e >> 6, c = e & 63;
            t[r][c] = S[h * 4096 + r * 64 + c];
        }
        __syncthreads();
#pragma unroll
        for (int j = 0; j < 16; j++) {
            int e = tid + j * 256, r = e >> 6, c = e & 63;
            D[h * 4096 + r * 64 + c] = __float2bfloat16(t[c][r]);
        }
    }
}

// ---- QKV GEMM: A (1024 x 1024 bf16), B^T; 128x64 tiles; outputs bf16.
// which==2 (V) writes transposed VT[d][l].
__global__ __launch_bounds__(256) void qkv_gemm128(const __hip_bfloat16* __restrict__ A,
                                                   const __hip_bfloat16* __restrict__ B0,
                                                   const __hip_bfloat16* __restrict__ B1,
                                                   const __hip_bfloat16* __restrict__ B2,
                                                   __hip_bfloat16* __restrict__ Qb,
                                                   __hip_bfloat16* __restrict__ Kb,
                                                   __hip_bfloat16* __restrict__ VT) {
    __shared__ __align__(16) char Abuf[128 * 128];
    __shared__ __align__(16) char Bbuf[64 * 128];
    const int tid = threadIdx.x;
    const int bm = blockIdx.y * 128;
    const int which = blockIdx.x >> 4;
    const int nb = blockIdx.x & 15;
    const __hip_bfloat16* B = (which == 0) ? B0 : (which == 1) ? B1 : B2;
    const int bn = nb * 64;
    const int wid = tid >> 6, lane = tid & 63;
    const int g = lane >> 4, r16 = lane & 15;
    const char* Ab = (const char*)A;
    const char* Bb = (const char*)B;
    f32x4 acc[2][4] = {};

    for (int kt = 0; kt < 16; kt++) {
        const int kbyte = kt * 128;
#pragma unroll
        for (int it = 0; it < 4; it++) {
            const int off = it * 4096 + tid * 16;
            const int row = off >> 7, cb = off & 127;
            __builtin_amdgcn_global_load_lds((gptr1)(Ab + (size_t)(bm + row) * 2048 + kbyte + SWZ(row, cb)),
                                             (lptr3)(Abuf + it * 4096 + wid * 1024), 16, 0, 0);
        }
#pragma unroll
        for (int it = 0; it < 2; it++) {
            const int off = it * 4096 + tid * 16;
            const int row = off >> 7, cb = off & 127;
            __builtin_amdgcn_global_load_lds((gptr1)(Bb + (size_t)(bn + row) * 2048 + kbyte + SWZ(row, cb)),
                                             (lptr3)(Bbuf + it * 4096 + wid * 1024), 16, 0, 0);
        }
        __syncthreads();
#pragma unroll
        for (int ks = 0; ks < 2; ks++) {
            short8 af[2], bfr[4];
#pragma unroll
            for (int m = 0; m < 2; m++)
                af[m] = ldfrag<128>(Abuf, wid * 32 + m * 16 + r16, ks * 32 + g * 8);
#pragma unroll
            for (int n = 0; n < 4; n++)
                bfr[n] = ldfrag<128>(Bbuf, n * 16 + r16, ks * 32 + g * 8);
#pragma unroll
            for (int m = 0; m < 2; m++)
#pragma unroll
                for (int n = 0; n < 4; n++)
                    acc[m][n] = __builtin_amdgcn_mfma_f32_16x16x32_bf16(af[m], bfr[n], acc[m][n], 0, 0, 0);
        }
        __syncthreads();
    }

    if (which == 2) {
        // V: write transposed VT[d][l], 4 consecutive l per lane -> ushort4
#pragma unroll
        for (int m = 0; m < 2; m++)
#pragma unroll
            for (int n = 0; n < 4; n++) {
                const int col = bn + n * 16 + r16;                 // d (V column)
                const int row0 = bm + wid * 32 + m * 16 + g * 4;   // l base
                ushort4 v;
                v.x = bf16bits(acc[m][n][0]); v.y = bf16bits(acc[m][n][1]);
                v.z = bf16bits(acc[m][n][2]); v.w = bf16bits(acc[m][n][3]);
                *(ushort4*)((unsigned short*)VT + (size_t)col * 1024 + row0) = v;
            }
    } else {
        __hip_bfloat16* C = (which == 0) ? Qb : Kb;
#pragma unroll
        for (int m = 0; m < 2; m++)
#pragma unroll
            for (int n = 0; n < 4; n++)
#pragma unroll
                for (int i = 0; i < 4; i++) {
                    const int row = bm + wid * 32 + m * 16 + g * 4 + i;
                    const int col = bn + n * 16 + r16;
                    *((unsigned short*)C + (size_t)row * 1024 + col) = bf16bits(acc[m][n][i]);
                }
    }
}

// ---- featmap: f = Xtile @ KT^T (bf16 in); feats = [softmax(f), softmax(-f)] clamped
__global__ __launch_bounds__(256) void featmap_mfma(const __hip_bfloat16* __restrict__ Qb,
                                                    const __hip_bfloat16* __restrict__ Kb,
                                                    const __hip_bfloat16* __restrict__ KqT,
                                                    const __hip_bfloat16* __restrict__ KkT,
                                                    __hip_bfloat16* __restrict__ qf,
                                                    __hip_bfloat16* __restrict__ kf,
                                                    __hip_bfloat16* __restrict__ kfT) {
    const bool kside = (blockIdx.z != 0);
    const __hip_bfloat16* X = kside ? Kb : Qb;
    const __hip_bfloat16* KT = kside ? KkT : KqT;
    __hip_bfloat16* feat = kside ? kf : qf;
    const int h = blockIdx.y, l0 = blockIdx.x * 64;
    __shared__ __align__(16) char Xs[64 * 128];
    __shared__ __align__(16) char Ks[64 * 128];
    __shared__ __align__(16) char ft[128 * 128];
    const int tid = threadIdx.x, lane = tid & 63, wid = tid >> 6;
    const int r16 = lane & 15, g = lane >> 4;

#pragma unroll
    for (int it = 0; it < 2; it++) {
        const int off = it * 4096 + tid * 16;
        const int row = off >> 7, cb = off & 127;
        __builtin_amdgcn_global_load_lds((gptr1)((const char*)X + (size_t)(l0 + row) * 2048 + h * 128 + SWZ(row, cb)),
                                         (lptr3)(Xs + it * 4096 + wid * 1024), 16, 0, 0);
        __builtin_amdgcn_global_load_lds((gptr1)((const char*)KT + (size_t)(h * 64 + row) * 128 + SWZ(row, cb)),
                                         (lptr3)(Ks + it * 4096 + wid * 1024), 16, 0, 0);
    }
    __syncthreads();

    f32x4 acc[4] = {};
#pragma unroll
    for (int ks = 0; ks < 2; ks++) {
        short8 a = ldfrag<128>(Xs, wid * 16 + r16, ks * 32 + g * 8);
#pragma unroll
        for (int n = 0; n < 4; n++) {
            short8 b = ldfrag<128>(Ks, n * 16 + r16, ks * 32 + g * 8);
            acc[n] = __builtin_amdgcn_mfma_f32_16x16x32_bf16(a, b, acc[n], 0, 0, 0);
        }
    }

#pragma unroll
    for (int i = 0; i < 4; i++) {
        const int row = wid * 16 + g * 4 + i;
        float m1 = acc[0][i], m2 = -acc[0][i];
#pragma unroll
        for (int n = 1; n < 4; n++) {
            m1 = fmaxf(m1, acc[n][i]);
            m2 = fmaxf(m2, -acc[n][i]);
        }
#pragma unroll
        for (int off = 8; off; off >>= 1) {
            m1 = fmaxf(m1, __shfl_xor(m1, off));
            m2 = fmaxf(m2, __shfl_xor(m2, off));
        }
        float e1[4], e2[4], s1 = 0.f, s2 = 0.f;
#pragma unroll
        for (int n = 0; n < 4; n++) {
            e1[n] = __expf(acc[n][i] - m1);  s1 += e1[n];
            e2[n] = __expf(-acc[n][i] - m2); s2 += e2[n];
        }
#pragma unroll
        for (int off = 8; off; off >>= 1) {
            s1 += __shfl_xor(s1, off);
            s2 += __shfl_xor(s2, off);
        }
        const float i1 = 1.f / s1, i2 = 1.f / s2;
        __hip_bfloat16* fo = feat + ((size_t)(h * 1024 + l0 + row)) * 128;
#pragma unroll
        for (int n = 0; n < 4; n++) {
            const int col = n * 16 + r16;
            unsigned short v1 = bf16bits(fmaxf(e1[n] * i1, 1e-12f));
            unsigned short v2 = bf16bits(fmaxf(e2[n] * i2, 1e-12f));
            *(unsigned short*)(fo + col) = v1;
            *(unsigned short*)(fo + col + 64) = v2;
            if (kside) {
                *(unsigned short*)(ft + col * 128 + SWZ(col, row * 2)) = v1;
                *(unsigned short*)(ft + (col + 64) * 128 + SWZ(col + 64, row * 2)) = v2;
            }
        }
    }
    if (kside) {
        __syncthreads();
#pragma unroll
        for (int j = 0; j < 4; j++) {
            const int off = (tid + j * 256) * 16;
            const int row = off >> 7, cb = off & 127;
            short8 v = *(const short8*)(ft + row * 128 + SWZ(row, cb));
            *(short8*)((char*)kfT + ((size_t)(h * 128 + row) * 1024 + l0) * 2 + cb) = v;
        }
    }
}

// ---- Sc[h][c][d][f] bf16 = V^T @ kf ; ksum f32
__global__ __launch_bounds__(256) void chunk_sums_mfma(const __hip_bfloat16* __restrict__ kfT,
                                                       const __hip_bfloat16* __restrict__ VT,
                                                       __hip_bfloat16* __restrict__ Scb,
                                                       float* __restrict__ ksum) {
    const int h = blockIdx.y, c = blockIdx.x, l0 = c * 64;
    __shared__ __align__(16) char VTs[64 * 128];
    __shared__ __align__(16) char KTs[128 * 128];
    const int tid = threadIdx.x, lane = tid & 63, wid = tid >> 6;
    const int r16 = lane & 15, g = lane >> 4;
#pragma unroll
    for (int it = 0; it < 2; it++) {
        const int off = it * 4096 + tid * 16;
        const int row = off >> 7, cb = off & 127;
        __builtin_amdgcn_global_load_lds((gptr1)((const char*)VT + ((size_t)(h * 64 + row) * 1024 + l0) * 2 + SWZ(row, cb)),
                                         (lptr3)(VTs + it * 4096 + wid * 1024), 16, 0, 0);
    }
#pragma unroll
    for (int it = 0; it < 4; it++) {
        const int off = it * 4096 + tid * 16;
        const int row = off >> 7, cb = off & 127;
        __builtin_amdgcn_global_load_lds((gptr1)((const char*)kfT + ((size_t)(h * 128 + row) * 1024 + l0) * 2 + SWZ(row, cb)),
                                         (lptr3)(KTs + it * 4096 + wid * 1024), 16, 0, 0);
    }
    __syncthreads();
    f32x4 acc[8] = {};
#pragma unroll
    for (int ks = 0; ks < 2; ks++) {
        short8 a = ldfrag<128>(VTs, wid * 16 + r16, ks * 32 + g * 8);
#pragma unroll
        for (int n = 0; n < 8; n++) {
            short8 b = ldfrag<128>(KTs, n * 16 + r16, ks * 32 + g * 8);
            acc[n] = __builtin_amdgcn_mfma_f32_16x16x32_bf16(a, b, acc[n], 0, 0, 0);
        }
    }
    unsigned short* o = (unsigned short*)Scb + (size_t)(h * NC + c) * 8192;
#pragma unroll
    for (int n = 0; n < 8; n++)
#pragma unroll
        for (int i = 0; i < 4; i++)
            o[(wid * 16 + g * 4 + i) * 128 + n * 16 + r16] = bf16bits(acc[n][i]);
    if (tid < 128) {
        float s = 0.f;
#pragma unroll 8
        for (int t = 0; t < 64; t++)
            s += b2f(*(const unsigned short*)(KTs + tid * 128 + SWZ(tid, t * 2)));
        ksum[(size_t)(h * NC + c) * 128 + tid] = s;
    }
}

// ---- exclusive prefix over chunks: Sp bf16 (f32 accum), kp f32
__global__ __launch_bounds__(256) void prefix_scan(const __hip_bfloat16* __restrict__ Scb,
                                                   __hip_bfloat16* __restrict__ Sp,
                                                   const float* __restrict__ ksum,
                                                   float* __restrict__ kp) {
    const int h = blockIdx.x, eb = blockIdx.y, tid = threadIdx.x;
#pragma unroll
    for (int j = 0; j < 4; j++) {
        const int e = eb * 1024 + tid + j * 256;
        float run = 0.f;
        for (int c = 0; c < NC; c++) {
            const size_t idx = (size_t)(h * NC + c) * 8192 + e;
            Sp[idx] = __float2bfloat16(run);
            run += b2f(((const unsigned short*)Scb)[idx]);
        }
    }
    if (eb == 0 && tid < 128) {
        float run = 0.f;
        for (int c = 0; c < NC; c++) {
            const size_t idx = (size_t)(h * NC + c) * 128 + tid;
            kp[idx] = run;
            run += ksum[idx];
        }
    }
}

// ---- chunk_out: Y = ((Qf Kf^T masked) V + Qf Sp^T) / z, bf16 out
__global__ __launch_bounds__(256) void chunk_out_mfma(const __hip_bfloat16* __restrict__ qf,
                                                      const __hip_bfloat16* __restrict__ kf,
                                                      const __hip_bfloat16* __restrict__ VT,
                                                      const __hip_bfloat16* __restrict__ Sp,
                                                      const float* __restrict__ kp,
                                                      __hip_bfloat16* __restrict__ Y) {
    const int h = blockIdx.y, c = blockIdx.x, l0 = c * 64;
    __shared__ __align__(16) char QF[64 * 256];
    __shared__ __align__(16) char KF[64 * 256];
    __shared__ __align__(16) char SP[64 * 256];
    __shared__ __align__(16) char VTs[64 * 128];
    __shared__ __align__(16) char AM[64 * 128];
    __shared__ float zi[64];
    __shared__ float invz[64];
    const int tid = threadIdx.x, lane = tid & 63, wid = tid >> 6;
    const int r16 = lane & 15, g = lane >> 4;

#pragma unroll
    for (int it = 0; it < 4; it++) {
        const int off = it * 4096 + wid * 1024 + lane * 16;
        const int row = off >> 8, cb = off & 255;
        const int sw = SWZ(row, cb);
        __builtin_amdgcn_global_load_lds((gptr1)((const char*)qf + ((size_t)(h * 1024 + l0 + row)) * 256 + sw),
                                         (lptr3)(QF + it * 4096 + wid * 1024), 16, 0, 0);
        __builtin_amdgcn_global_load_lds((gptr1)((const char*)kf + ((size_t)(h * 1024 + l0 + row)) * 256 + sw),
                                         (lptr3)(KF + it * 4096 + wid * 1024), 16, 0, 0);
        __builtin_amdgcn_global_load_lds((gptr1)((const char*)Sp + ((size_t)((h * NC + c) * 64 + row)) * 256 + sw),
                                         (lptr3)(SP + it * 4096 + wid * 1024), 16, 0, 0);
    }
#pragma unroll
    for (int it = 0; it < 2; it++) {
        const int off = it * 4096 + wid * 1024 + lane * 16;
        const int row = off >> 7, cb = off & 127;
        __builtin_amdgcn_global_load_lds((gptr1)((const char*)VT + ((size_t)(h * 64 + row) * 1024 + l0) * 2 + SWZ(row, cb)),
                                         (lptr3)(VTs + it * 4096 + wid * 1024), 16, 0, 0);
    }
    __syncthreads();

    f32x4 a4[4] = {};
#pragma unroll
    for (int ks = 0; ks < 4; ks++) {
        short8 a = ldfrag<256>(QF, wid * 16 + r16, ks * 32 + g * 8);
#pragma unroll
        for (int n = 0; n < 4; n++) {
            short8 b = ldfrag<256>(KF, n * 16 + r16, ks * 32 + g * 8);
            a4[n] = __builtin_amdgcn_mfma_f32_16x16x32_bf16(a, b, a4[n], 0, 0, 0);
        }
    }
    const int rowl = wid * 16 + g * 4;
#pragma unroll
    for (int i = 0; i < 4; i++) {
        float r = 0.f;
#pragma unroll
        for (int n = 0; n < 4; n++) {
            const int col = n * 16 + r16;
            float v = (col <= rowl + i) ? a4[n][i] : 0.f;
            a4[n][i] = v;
            r += v;
        }
#pragma unroll
        for (int off = 8; off; off >>= 1) r += __shfl_xor(r, off);
        if (r16 == 0) zi[rowl + i] = r;
#pragma unroll
        for (int n = 0; n < 4; n++)
            *(unsigned short*)(AM + (rowl + i) * 128 + SWZ(rowl + i, (n * 16 + r16) * 2)) = bf16bits(a4[n][i]);
    }
    __syncthreads();

    if (tid < 64) {
        float z = zi[tid] + 1e-12f;
        const float* kpp = kp + (size_t)(h * NC + c) * 128;
#pragma unroll 8
        for (int f = 0; f < 128; f++)
            z += b2f(*(const unsigned short*)(QF + tid * 256 + SWZ(tid, f * 2))) * kpp[f];
        invz[tid] = 1.f / z;
    }

    f32x4 o4[4] = {};
#pragma unroll
    for (int ks = 0; ks < 2; ks++) {
        short8 a = ldfrag<128>(AM, wid * 16 + r16, ks * 32 + g * 8);
#pragma unroll
        for (int n = 0; n < 4; n++) {
            short8 b = ldfrag<128>(VTs, n * 16 + r16, ks * 32 + g * 8);
            o4[n] = __builtin_amdgcn_mfma_f32_16x16x32_bf16(a, b, o4[n], 0, 0, 0);
        }
    }
#pragma unroll
    for (int ks = 0; ks < 4; ks++) {
        short8 a = ldfrag<256>(QF, wid * 16 + r16, ks * 32 + g * 8);
#pragma unroll
        for (int n = 0; n < 4; n++) {
            short8 b = ldfrag<256>(SP, n * 16 + r16, ks * 32 + g * 8);
            o4[n] = __builtin_amdgcn_mfma_f32_16x16x32_bf16(a, b, o4[n], 0, 0, 0);
        }
    }
    __syncthreads();
#pragma unroll
    for (int n = 0; n < 4; n++)
#pragma unroll
        for (int i = 0; i < 4; i++) {
            const int row = rowl + i, col = n * 16 + r16;
            Y[((size_t)(l0 + row)) * 1024 + h * 64 + col] = __float2bfloat16(o4[n][i] * invz[row]);
        }
}

// ---- final GEMM: A bf16 (M x K), B^T bf16 (N x K), C f32 (validated r1 structure)
__global__ __launch_bounds__(256) void gemm_final(const __hip_bfloat16* __restrict__ A,
                                                  const __hip_bfloat16* __restrict__ B,
                                                  float* __restrict__ C) {
    __shared__ __align__(16) char Abuf[64 * 128];
    __shared__ __align__(16) char Bbuf[64 * 128];
    const int tid = threadIdx.x;
    const int bm = blockIdx.y * 64, bn = blockIdx.x * 64;
    const int wid = tid >> 6, lane = tid & 63;
    const int g = lane >> 4, r16 = lane & 15;
    const int wr = wid >> 1, wc = wid & 1;
    const char* Ab = (const char*)A;
    const char* Bb = (const char*)B;
    f32x4 acc[2][2] = {};
    for (int kt = 0; kt < 16; kt++) {
        const int kbyte = kt * 128;
#pragma unroll
        for (int it = 0; it < 2; it++) {
            const int off = it * 4096 + tid * 16;
            const int row = off >> 7, cb = off & 127;
            __builtin_amdgcn_global_load_lds((gptr1)(Ab + (size_t)(bm + row) * 2048 + kbyte + SWZ(row, cb)),
                                             (lptr3)(Abuf + it * 4096 + wid * 1024), 16, 0, 0);
            __builtin_amdgcn_global_load_lds((gptr1)(Bb + (size_t)(bn + row) * 2048 + kbyte + SWZ(row, cb)),
                                             (lptr3)(Bbuf + it * 4096 + wid * 1024), 16, 0, 0);
        }
        __syncthreads();
#pragma unroll
        for (int ks = 0; ks < 2; ks++) {
            short8 af[2], bfr[2];
#pragma unroll
            for (int m = 0; m < 2; m++)
                af[m] = ldfrag<128>(Abuf, wr * 32 + m * 16 + r16, ks * 32 + g * 8);
#pragma unroll
            for (int n = 0; n < 2; n++)
                bfr[n] = ldfrag<128>(Bbuf, wc * 32 + n * 16 + r16, ks * 32 + g * 8);
#pragma unroll
            for (int m = 0; m < 2; m++)
#pragma unroll
                for (int n = 0; n < 2; n++)
                    acc[m][n] = __builtin_amdgcn_mfma_f32_16x16x32_bf16(af[m], bfr[n], acc[m][n], 0, 0, 0);
        }
        __syncthreads();
    }
#pragma unroll
    for (int m = 0; m < 2; m++)
#pragma unroll
        for (int n = 0; n < 2; n++)
#pragma unroll
            for (int i = 0; i < 4; i++) {
                const int row = bm + wr * 32 + m * 16 + g * 4 + i;
                const int col = bn + wc * 32 + n * 16 + r16;
                C[(size_t)row * 1024 + col] = acc[m][n][i];
            }
}

extern "C" void kernel_launch(void* const* d_in, const int* in_sizes, int n_in,
                              void* d_out, int out_size, void* d_ws, size_t ws_size,
                              hipStream_t stream) {
    const float* x  = (const float*)d_in[0];
    const float* Wq = (const float*)d_in[1];
    const float* Wk = (const float*)d_in[2];
    const float* Wv = (const float*)d_in[3];
    const float* Wo = (const float*)d_in[4];
    const float* Kq = (const float*)d_in[5];
    const float* Kk = (const float*)d_in[6];
    float* out = (float*)d_out;
    float* ws = (float*)d_ws;

    const size_t M1 = 1024 * 1024;
    if (ws_size < 10 * M1 * sizeof(float)) return;

    __hip_bfloat16* Qb  = (__hip_bfloat16*)(ws);                  // [0, 0.5M)
    __hip_bfloat16* Kb  = (__hip_bfloat16*)(ws + M1 / 2);         // [0.5, 1)
    __hip_bfloat16* VT  = (__hip_bfloat16*)(ws + 1 * M1);         // [1, 1.5)
    __hip_bfloat16* xb  = (__hip_bfloat16*)(ws + 3 * M1 / 2);     // [1.5, 2)
    __hip_bfloat16* Wqt = (__hip_bfloat16*)(ws + 2 * M1);         // [2, 2.5)
    __hip_bfloat16* Wkt = (__hip_bfloat16*)(ws + 5 * M1 / 2);     // [2.5, 3)
    __hip_bfloat16* Wvt = (__hip_bfloat16*)(ws + 3 * M1);         // [3, 3.5)
    __hip_bfloat16* Wot = (__hip_bfloat16*)(ws + 7 * M1 / 2);     // [3.5, 4)
    __hip_bfloat16* KqT = (__hip_bfloat16*)(ws + 4 * M1);         // 64K elems
    __hip_bfloat16* KkT = (__hip_bfloat16*)(ws + 4 * M1 + 32768);
    __hip_bfloat16* qfb = (__hip_bfloat16*)(ws + 4 * M1 + M1 / 4);        // [4.25, 5.25)
    __hip_bfloat16* kfb = (__hip_bfloat16*)(ws + 5 * M1 + M1 / 4);        // [5.25, 6.25)
    __hip_bfloat16* kfT = (__hip_bfloat16*)(ws + 6 * M1 + M1 / 4);        // [6.25, 7.25)
    __hip_bfloat16* Scb = (__hip_bfloat16*)(ws + 7 * M1 + M1 / 4);        // [7.25, 8.25)
    __hip_bfloat16* Spb = (__hip_bfloat16*)(ws + 8 * M1 + M1 / 4);        // [8.25, 9.25)
    __hip_bfloat16* Yb  = (__hip_bfloat16*)(ws + 9 * M1 + M1 / 4);        // [9.25, 9.75)
    float* ksum = ws + 9 * M1 + 3 * M1 / 4;                               // 32K f32
    float* kp   = ws + 9 * M1 + 3 * M1 / 4 + 32768;                       // 32K f32

    prep<<<dim3(32, 32, 6), dim3(32, 8), 0, stream>>>(x, Wq, Wk, Wv, Wo, Kq, Kk,
                                                      xb, Wqt, Wkt, Wvt, Wot, KqT, KkT);
    qkv_gemm128<<<dim3(48, 8), 256, 0, stream>>>(xb, Wqt, Wkt, Wvt, Qb, Kb, VT);
    featmap_mfma<<<dim3(16, 16, 2), 256, 0, stream>>>(Qb, Kb, KqT, KkT, qfb, kfb, kfT);
    chunk_sums_mfma<<<dim3(NC, NH), 256, 0, stream>>>(kfT, VT, Scb, ksum);
    prefix_scan<<<dim3(NH, 8), 256, 0, stream>>>(Scb, Spb, ksum, kp);
    chunk_out_mfma<<<dim3(NC, NH), 256, 0, stream>>>(qfb, kfb, VT, Spb, kp, Yb);
    gemm_final<<<dim3(16, 16), 256, 0, stream>>>(Yb, Wot, out);
}

// Round 5
// 55.256 us; speedup vs baseline: 5.1955x; 1.2928x over previous
//
#include <hip/hip_runtime.h>
#include <hip/hip_bf16.h>

// Hedgehog linear attention, B=1, L=1024, D=1024, H=16, HD=64, FD=64.
// Round 5: featmap fused into QKV-GEMM epilogue; 2-phase double-buffered
// GEMM K-loops (counted vmcnt, 2 barriers/iter); 6 launches.
//  1) prep: W^T bf16 (x4), x bf16, Kq/Kk^T bf16
//  2) qkv_feat: per (which,nb=head,bm): GEMM tile 128x64 -> epilogue:
//       which=0/1: feature MFMA + softmax -> qf / (kf + kfT);  which=2: VT
//  3) chunk_sums_mfma: Sc bf16 = V^T @ kf, ksum f32
//  4) prefix_scan: Sp bf16 (f32 accum), kp f32
//  5) chunk_out_mfma: Y bf16
//  6) gemm_final: out f32 = Y @ Wo (2-phase dbuf)

#define NH 16
#define NC 16

using short8 = __attribute__((ext_vector_type(8))) short;
using f32x4  = __attribute__((ext_vector_type(4))) float;
typedef const __attribute__((address_space(1))) char* gptr1;
typedef __attribute__((address_space(3))) char* lptr3;

static __device__ __forceinline__ unsigned short bf16bits(float x) {
    __hip_bfloat16 h = __float2bfloat16(x);
    return __builtin_bit_cast(unsigned short, h);
}
static __device__ __forceinline__ float b2f(unsigned short u) {
    return __builtin_bit_cast(float, (unsigned int)u << 16);
}
#define SWZ(row, cb) ((cb) ^ (((row) & 7) << 4))

template<int RS>
static __device__ __forceinline__ short8 ldfrag(const char* buf, int row, int kelem) {
    return *(const short8*)(buf + row * RS + SWZ(row, kelem * 2));
}

// ---- fused prep: z<4 weight transpose+convert; z==4 x convert; z==5 kmat transpose
__global__ __launch_bounds__(256) void prep(const float* __restrict__ x,
                                            const float* __restrict__ w0,
                                            const float* __restrict__ w1,
                                            const float* __restrict__ w2,
                                            const float* __restrict__ w3,
                                            const float* __restrict__ Kq,
                                            const float* __restrict__ Kk,
                                            __hip_bfloat16* __restrict__ xb,
                                            __hip_bfloat16* __restrict__ d0,
                                            __hip_bfloat16* __restrict__ d1,
                                            __hip_bfloat16* __restrict__ d2,
                                            __hip_bfloat16* __restrict__ d3,
                                            __hip_bfloat16* __restrict__ KqT,
                                            __hip_bfloat16* __restrict__ KkT) {
    const int z = blockIdx.z;
    const int tx = threadIdx.x, ty = threadIdx.y;
    const int tid = ty * 32 + tx;
    if (z < 4) {
        const float* src = (z == 0) ? w0 : (z == 1) ? w1 : (z == 2) ? w2 : w3;
        __hip_bfloat16* dst = (z == 0) ? d0 : (z == 1) ? d1 : (z == 2) ? d2 : d3;
        __shared__ float tile[32][33];
        const int bx = blockIdx.x * 32, by = blockIdx.y * 32;
#pragma unroll
        for (int i = 0; i < 32; i += 8)
            tile[ty + i][tx] = src[(by + ty + i) * 1024 + bx + tx];
        __syncthreads();
#pragma unroll
        for (int i = 0; i < 32; i += 8)
            dst[(size_t)(bx + ty + i) * 1024 + by + tx] = __float2bfloat16(tile[tx][ty + i]);
    } else if (z == 4) {
        const int blk = blockIdx.y * 32 + blockIdx.x;
        const int i = (blk * 256 + tid) * 4;
        float4 v = *(const float4*)(x + i);
        ushort4 o;
        o.x = bf16bits(v.x); o.y = bf16bits(v.y); o.z = bf16bits(v.z); o.w = bf16bits(v.w);
        *(ushort4*)((unsigned short*)xb + i) = o;
    } else {
        if (blockIdx.y != 0 || blockIdx.x >= 32) return;
        const int h = blockIdx.x & 15;
        const float* S = (blockIdx.x >> 4) ? Kk : Kq;
        __hip_bfloat16* D = (blockIdx.x >> 4) ? KkT : KqT;
        __shared__ float t[64][65];
#pragma unroll
        for (int j = 0; j < 16; j++) {
            int e = tid + j * 256, r = e >> 6, c = e & 63;
            t[r][c] = S[h * 4096 + r * 64 + c];
        }
        __syncthreads();
#pragma unroll
        for (int j = 0; j < 16; j++) {
            int e = tid + j * 256, r = e >> 6, c = e & 63;
            D[h * 4096 + r * 64 + c] = __float2bfloat16(t[c][r]);
        }
    }
}

// ---- QKV GEMM + fused feature map.
// A (1024x1024 bf16), B^T per which; tile 128x64; 2-phase dbuf K-loop.
// which==0: qf; which==1: kf + kfT; which==2: VT (transposed epilogue).
__global__ __launch_bounds__(256) void qkv_feat(const __hip_bfloat16* __restrict__ A,
                                                const __hip_bfloat16* __restrict__ B0,
                                                const __hip_bfloat16* __restrict__ B1,
                                                const __hip_bfloat16* __restrict__ B2,
                                                const __hip_bfloat16* __restrict__ KqT,
                                                const __hip_bfloat16* __restrict__ KkT,
                                                __hip_bfloat16* __restrict__ qf,
                                                __hip_bfloat16* __restrict__ kf,
                                                __hip_bfloat16* __restrict__ kfT,
                                                __hip_bfloat16* __restrict__ VT) {
    // smem: [0,16K) A0 | [16K,32K) A1 | [32K,40K) B0 | [40K,48K) B1
    // epilogue: KT at [0,8K); Xs at [32K,48K); ft at [0,32K)
    __shared__ __align__(16) char smem[49152];
    const int tid = threadIdx.x;
    const int bm = blockIdx.y * 128;
    const int which = blockIdx.x >> 4;
    const int h = blockIdx.x & 15;          // head == n-tile
    const __hip_bfloat16* B = (which == 0) ? B0 : (which == 1) ? B1 : B2;
    const int bn = h * 64;
    const int wid = tid >> 6, lane = tid & 63;
    const int g = lane >> 4, r16 = lane & 15;
    const char* Ab = (const char*)A;
    const char* Bb = (const char*)B;
    f32x4 acc[2][4] = {};

#define QKV_STAGE(dstA, dstB, kbyte)                                                                   \
    do {                                                                                               \
        _Pragma("unroll") for (int it = 0; it < 4; it++) {                                             \
            const int off = it * 4096 + tid * 16;                                                      \
            const int row = off >> 7, cb = off & 127;                                                  \
            __builtin_amdgcn_global_load_lds((gptr1)(Ab + (size_t)(bm + row) * 2048 + (kbyte) + SWZ(row, cb)), \
                                             (lptr3)((dstA) + it * 4096 + wid * 1024), 16, 0, 0);      \
        }                                                                                              \
        _Pragma("unroll") for (int it = 0; it < 2; it++) {                                             \
            const int off = it * 4096 + tid * 16;                                                      \
            const int row = off >> 7, cb = off & 127;                                                  \
            __builtin_amdgcn_global_load_lds((gptr1)(Bb + (size_t)(bn + row) * 2048 + (kbyte) + SWZ(row, cb)), \
                                             (lptr3)((dstB) + it * 4096 + wid * 1024), 16, 0, 0);      \
        }                                                                                              \
    } while (0)

    QKV_STAGE(smem, smem + 32768, 0);
    for (int kt = 0; kt < 16; kt++) {
        char* Ac = smem + ((kt & 1) ? 16384 : 0);
        char* Bc = smem + 32768 + ((kt & 1) ? 8192 : 0);
        if (kt < 15) {
            char* An = smem + ((kt & 1) ? 0 : 16384);
            char* Bn = smem + 32768 + ((kt & 1) ? 0 : 8192);
            QKV_STAGE(An, Bn, (kt + 1) * 128);
            asm volatile("s_waitcnt vmcnt(6)" ::: "memory");
        } else {
            asm volatile("s_waitcnt vmcnt(0)" ::: "memory");
        }
        __builtin_amdgcn_s_barrier();
#pragma unroll
        for (int ks = 0; ks < 2; ks++) {
            short8 af[2], bfr[4];
#pragma unroll
            for (int m = 0; m < 2; m++)
                af[m] = ldfrag<128>(Ac, wid * 32 + m * 16 + r16, ks * 32 + g * 8);
#pragma unroll
            for (int n = 0; n < 4; n++)
                bfr[n] = ldfrag<128>(Bc, n * 16 + r16, ks * 32 + g * 8);
#pragma unroll
            for (int m = 0; m < 2; m++)
#pragma unroll
                for (int n = 0; n < 4; n++)
                    acc[m][n] = __builtin_amdgcn_mfma_f32_16x16x32_bf16(af[m], bfr[n], acc[m][n], 0, 0, 0);
        }
        asm volatile("s_waitcnt lgkmcnt(0)" ::: "memory");
        __builtin_amdgcn_s_barrier();
    }
#undef QKV_STAGE

    if (which == 2) {
        // V: write transposed VT[d][l]
#pragma unroll
        for (int m = 0; m < 2; m++)
#pragma unroll
            for (int n = 0; n < 4; n++) {
                const int col = bn + n * 16 + r16;                 // d
                const int row0 = bm + wid * 32 + m * 16 + g * 4;   // l
                ushort4 v;
                v.x = bf16bits(acc[m][n][0]); v.y = bf16bits(acc[m][n][1]);
                v.z = bf16bits(acc[m][n][2]); v.w = bf16bits(acc[m][n][3]);
                *(ushort4*)((unsigned short*)VT + (size_t)col * 1024 + row0) = v;
            }
        return;
    }

    // ---- fused feature map epilogue (which 0/1) ----
    const bool kside = (which == 1);
    char* XS = smem + 32768;   // 128 rows x 128B (bf16 x[l][d])
    // write acc as bf16 into XS (swizzled)
#pragma unroll
    for (int m = 0; m < 2; m++)
#pragma unroll
        for (int n = 0; n < 4; n++)
#pragma unroll
            for (int i = 0; i < 4; i++) {
                const int row = wid * 32 + m * 16 + g * 4 + i;
                *(unsigned short*)(XS + row * 128 + SWZ(row, (n * 16 + r16) * 2)) = bf16bits(acc[m][n][i]);
            }
    // stage KT[h] (64 fd x 64 d bf16 = 8KB) into smem[0,8K)
    {
        const char* KTp = (const char*)(kside ? KkT : KqT);
#pragma unroll
        for (int it = 0; it < 2; it++) {
            const int off = it * 4096 + tid * 16;
            const int row = off >> 7, cb = off & 127;
            __builtin_amdgcn_global_load_lds((gptr1)(KTp + (size_t)(h * 64 + row) * 128 + SWZ(row, cb)),
                                             (lptr3)(smem + it * 4096 + wid * 1024), 16, 0, 0);
        }
    }
    __syncthreads();

    // f = X @ KT^T   (K=64)
    f32x4 fr[2][4] = {};
#pragma unroll
    for (int ks = 0; ks < 2; ks++) {
        short8 af[2], bfr[4];
#pragma unroll
        for (int m = 0; m < 2; m++)
            af[m] = ldfrag<128>(XS, wid * 32 + m * 16 + r16, ks * 32 + g * 8);
#pragma unroll
        for (int n = 0; n < 4; n++)
            bfr[n] = ldfrag<128>(smem, n * 16 + r16, ks * 32 + g * 8);
#pragma unroll
        for (int m = 0; m < 2; m++)
#pragma unroll
            for (int n = 0; n < 4; n++)
                fr[m][n] = __builtin_amdgcn_mfma_f32_16x16x32_bf16(af[m], bfr[n], fr[m][n], 0, 0, 0);
    }
    if (kside) __syncthreads();   // KT dead before ft overwrites smem[0,32K)

    char* ft = smem;              // 128 fd-rows x 256B (bf16 [fd][l]) -- kside only
    __hip_bfloat16* feat = kside ? kf : qf;
#pragma unroll
    for (int m = 0; m < 2; m++)
#pragma unroll
        for (int i = 0; i < 4; i++) {
            const int row = wid * 32 + m * 16 + g * 4 + i;   // l within tile
            float m1 = fr[m][0][i], m2 = -fr[m][0][i];
#pragma unroll
            for (int n = 1; n < 4; n++) {
                m1 = fmaxf(m1, fr[m][n][i]);
                m2 = fmaxf(m2, -fr[m][n][i]);
            }
#pragma unroll
            for (int off = 8; off; off >>= 1) {
                m1 = fmaxf(m1, __shfl_xor(m1, off));
                m2 = fmaxf(m2, __shfl_xor(m2, off));
            }
            float e1[4], e2[4], s1 = 0.f, s2 = 0.f;
#pragma unroll
            for (int n = 0; n < 4; n++) {
                e1[n] = __expf(fr[m][n][i] - m1);  s1 += e1[n];
                e2[n] = __expf(-fr[m][n][i] - m2); s2 += e2[n];
            }
#pragma unroll
            for (int off = 8; off; off >>= 1) {
                s1 += __shfl_xor(s1, off);
                s2 += __shfl_xor(s2, off);
            }
            const float i1 = 1.f / s1, i2 = 1.f / s2;
            __hip_bfloat16* fo = feat + ((size_t)(h * 1024 + bm + row)) * 128;
#pragma unroll
            for (int n = 0; n < 4; n++) {
                const int col = n * 16 + r16;
                unsigned short v1 = bf16bits(fmaxf(e1[n] * i1, 1e-12f));
                unsigned short v2 = bf16bits(fmaxf(e2[n] * i2, 1e-12f));
                *(unsigned short*)(fo + col) = v1;
                *(unsigned short*)(fo + col + 64) = v2;
                if (kside) {
                    *(unsigned short*)(ft + col * 256 + SWZ(col, row * 2)) = v1;
                    *(unsigned short*)(ft + (col + 64) * 256 + SWZ(col + 64, row * 2)) = v2;
                }
            }
        }
    if (kside) {
        __syncthreads();
        // coalesced kfT write: [h][128 fd][1024 l], cols bm..bm+127
#pragma unroll
        for (int j = 0; j < 8; j++) {
            const int off = (tid + j * 256) * 16;
            const int row = off >> 8, cb = off & 255;
            short8 v = *(const short8*)(ft + row * 256 + SWZ(row, cb));
            *(short8*)((char*)kfT + ((size_t)(h * 128 + row) * 1024 + bm) * 2 + cb) = v;
        }
    }
}

// ---- Sc[h][c][d][f] bf16 = V^T @ kf ; ksum f32
__global__ __launch_bounds__(256) void chunk_sums_mfma(const __hip_bfloat16* __restrict__ kfT,
                                                       const __hip_bfloat16* __restrict__ VT,
                                                       __hip_bfloat16* __restrict__ Scb,
                                                       float* __restrict__ ksum) {
    const int h = blockIdx.y, c = blockIdx.x, l0 = c * 64;
    __shared__ __align__(16) char VTs[64 * 128];
    __shared__ __align__(16) char KTs[128 * 128];
    const int tid = threadIdx.x, lane = tid & 63, wid = tid >> 6;
    const int r16 = lane & 15, g = lane >> 4;
#pragma unroll
    for (int it = 0; it < 2; it++) {
        const int off = it * 4096 + tid * 16;
        const int row = off >> 7, cb = off & 127;
        __builtin_amdgcn_global_load_lds((gptr1)((const char*)VT + ((size_t)(h * 64 + row) * 1024 + l0) * 2 + SWZ(row, cb)),
                                         (lptr3)(VTs + it * 4096 + wid * 1024), 16, 0, 0);
    }
#pragma unroll
    for (int it = 0; it < 4; it++) {
        const int off = it * 4096 + tid * 16;
        const int row = off >> 7, cb = off & 127;
        __builtin_amdgcn_global_load_lds((gptr1)((const char*)kfT + ((size_t)(h * 128 + row) * 1024 + l0) * 2 + SWZ(row, cb)),
                                         (lptr3)(KTs + it * 4096 + wid * 1024), 16, 0, 0);
    }
    __syncthreads();
    f32x4 acc[8] = {};
#pragma unroll
    for (int ks = 0; ks < 2; ks++) {
        short8 a = ldfrag<128>(VTs, wid * 16 + r16, ks * 32 + g * 8);
#pragma unroll
        for (int n = 0; n < 8; n++) {
            short8 b = ldfrag<128>(KTs, n * 16 + r16, ks * 32 + g * 8);
            acc[n] = __builtin_amdgcn_mfma_f32_16x16x32_bf16(a, b, acc[n], 0, 0, 0);
        }
    }
    unsigned short* o = (unsigned short*)Scb + (size_t)(h * NC + c) * 8192;
#pragma unroll
    for (int n = 0; n < 8; n++)
#pragma unroll
        for (int i = 0; i < 4; i++)
            o[(wid * 16 + g * 4 + i) * 128 + n * 16 + r16] = bf16bits(acc[n][i]);
    if (tid < 128) {
        float s = 0.f;
#pragma unroll 8
        for (int t = 0; t < 64; t++)
            s += b2f(*(const unsigned short*)(KTs + tid * 128 + SWZ(tid, t * 2)));
        ksum[(size_t)(h * NC + c) * 128 + tid] = s;
    }
}

// ---- exclusive prefix over chunks: Sp bf16 (f32 accum), kp f32
__global__ __launch_bounds__(256) void prefix_scan(const __hip_bfloat16* __restrict__ Scb,
                                                   __hip_bfloat16* __restrict__ Sp,
                                                   const float* __restrict__ ksum,
                                                   float* __restrict__ kp) {
    const int h = blockIdx.x, eb = blockIdx.y, tid = threadIdx.x;
#pragma unroll
    for (int j = 0; j < 4; j++) {
        const int e = eb * 1024 + tid + j * 256;
        float v[NC];
#pragma unroll
        for (int c = 0; c < NC; c++)
            v[c] = b2f(((const unsigned short*)Scb)[(size_t)(h * NC + c) * 8192 + e]);
        float run = 0.f;
#pragma unroll
        for (int c = 0; c < NC; c++) {
            Sp[(size_t)(h * NC + c) * 8192 + e] = __float2bfloat16(run);
            run += v[c];
        }
    }
    if (eb == 0 && tid < 128) {
        float run = 0.f;
#pragma unroll
        for (int c = 0; c < NC; c++) {
            const size_t idx = (size_t)(h * NC + c) * 128 + tid;
            kp[idx] = run;
            run += ksum[idx];
        }
    }
}

// ---- chunk_out: Y = ((Qf Kf^T masked) V + Qf Sp^T) / z, bf16 out
__global__ __launch_bounds__(256) void chunk_out_mfma(const __hip_bfloat16* __restrict__ qf,
                                                      const __hip_bfloat16* __restrict__ kf,
                                                      const __hip_bfloat16* __restrict__ VT,
                                                      const __hip_bfloat16* __restrict__ Sp,
                                                      const float* __restrict__ kp,
                                                      __hip_bfloat16* __restrict__ Y) {
    const int h = blockIdx.y, c = blockIdx.x, l0 = c * 64;
    __shared__ __align__(16) char QF[64 * 256];
    __shared__ __align__(16) char KF[64 * 256];
    __shared__ __align__(16) char SP[64 * 256];
    __shared__ __align__(16) char VTs[64 * 128];
    __shared__ __align__(16) char AM[64 * 128];
    __shared__ float zi[64];
    __shared__ float invz[64];
    const int tid = threadIdx.x, lane = tid & 63, wid = tid >> 6;
    const int r16 = lane & 15, g = lane >> 4;

#pragma unroll
    for (int it = 0; it < 4; it++) {
        const int off = it * 4096 + wid * 1024 + lane * 16;
        const int row = off >> 8, cb = off & 255;
        const int sw = SWZ(row, cb);
        __builtin_amdgcn_global_load_lds((gptr1)((const char*)qf + ((size_t)(h * 1024 + l0 + row)) * 256 + sw),
                                         (lptr3)(QF + it * 4096 + wid * 1024), 16, 0, 0);
        __builtin_amdgcn_global_load_lds((gptr1)((const char*)kf + ((size_t)(h * 1024 + l0 + row)) * 256 + sw),
                                         (lptr3)(KF + it * 4096 + wid * 1024), 16, 0, 0);
        __builtin_amdgcn_global_load_lds((gptr1)((const char*)Sp + ((size_t)((h * NC + c) * 64 + row)) * 256 + sw),
                                         (lptr3)(SP + it * 4096 + wid * 1024), 16, 0, 0);
    }
#pragma unroll
    for (int it = 0; it < 2; it++) {
        const int off = it * 4096 + wid * 1024 + lane * 16;
        const int row = off >> 7, cb = off & 127;
        __builtin_amdgcn_global_load_lds((gptr1)((const char*)VT + ((size_t)(h * 64 + row) * 1024 + l0) * 2 + SWZ(row, cb)),
                                         (lptr3)(VTs + it * 4096 + wid * 1024), 16, 0, 0);
    }
    __syncthreads();

    f32x4 a4[4] = {};
#pragma unroll
    for (int ks = 0; ks < 4; ks++) {
        short8 a = ldfrag<256>(QF, wid * 16 + r16, ks * 32 + g * 8);
#pragma unroll
        for (int n = 0; n < 4; n++) {
            short8 b = ldfrag<256>(KF, n * 16 + r16, ks * 32 + g * 8);
            a4[n] = __builtin_amdgcn_mfma_f32_16x16x32_bf16(a, b, a4[n], 0, 0, 0);
        }
    }
    const int rowl = wid * 16 + g * 4;
#pragma unroll
    for (int i = 0; i < 4; i++) {
        float r = 0.f;
#pragma unroll
        for (int n = 0; n < 4; n++) {
            const int col = n * 16 + r16;
            float v = (col <= rowl + i) ? a4[n][i] : 0.f;
            a4[n][i] = v;
            r += v;
        }
#pragma unroll
        for (int off = 8; off; off >>= 1) r += __shfl_xor(r, off);
        if (r16 == 0) zi[rowl + i] = r;
#pragma unroll
        for (int n = 0; n < 4; n++)
            *(unsigned short*)(AM + (rowl + i) * 128 + SWZ(rowl + i, (n * 16 + r16) * 2)) = bf16bits(a4[n][i]);
    }
    __syncthreads();

    if (tid < 64) {
        float z = zi[tid] + 1e-12f;
        const float* kpp = kp + (size_t)(h * NC + c) * 128;
#pragma unroll 8
        for (int f = 0; f < 128; f++)
            z += b2f(*(const unsigned short*)(QF + tid * 256 + SWZ(tid, f * 2))) * kpp[f];
        invz[tid] = 1.f / z;
    }

    f32x4 o4[4] = {};
#pragma unroll
    for (int ks = 0; ks < 2; ks++) {
        short8 a = ldfrag<128>(AM, wid * 16 + r16, ks * 32 + g * 8);
#pragma unroll
        for (int n = 0; n < 4; n++) {
            short8 b = ldfrag<128>(VTs, n * 16 + r16, ks * 32 + g * 8);
            o4[n] = __builtin_amdgcn_mfma_f32_16x16x32_bf16(a, b, o4[n], 0, 0, 0);
        }
    }
#pragma unroll
    for (int ks = 0; ks < 4; ks++) {
        short8 a = ldfrag<256>(QF, wid * 16 + r16, ks * 32 + g * 8);
#pragma unroll
        for (int n = 0; n < 4; n++) {
            short8 b = ldfrag<256>(SP, n * 16 + r16, ks * 32 + g * 8);
            o4[n] = __builtin_amdgcn_mfma_f32_16x16x32_bf16(a, b, o4[n], 0, 0, 0);
        }
    }
    __syncthreads();
#pragma unroll
    for (int n = 0; n < 4; n++)
#pragma unroll
        for (int i = 0; i < 4; i++) {
            const int row = rowl + i, col = n * 16 + r16;
            Y[((size_t)(l0 + row)) * 1024 + h * 64 + col] = __float2bfloat16(o4[n][i] * invz[row]);
        }
}

// ---- final GEMM: A bf16 (M x K), B^T bf16 (N x K), C f32; 64x64 tiles, 2-phase dbuf
__global__ __launch_bounds__(256) void gemm_final(const __hip_bfloat16* __restrict__ A,
                                                  const __hip_bfloat16* __restrict__ B,
                                                  float* __restrict__ C) {
    // smem: [0,8K) A0 | [8K,16K) A1 | [16K,24K) B0 | [24K,32K) B1
    __shared__ __align__(16) char smem[32768];
    const int tid = threadIdx.x;
    const int bm = blockIdx.y * 64, bn = blockIdx.x * 64;
    const int wid = tid >> 6, lane = tid & 63;
    const int g = lane >> 4, r16 = lane & 15;
    const int wr = wid >> 1, wc = wid & 1;
    const char* Ab = (const char*)A;
    const char* Bb = (const char*)B;
    f32x4 acc[2][2] = {};

#define FIN_STAGE(dstA, dstB, kbyte)                                                                   \
    do {                                                                                               \
        _Pragma("unroll") for (int it = 0; it < 2; it++) {                                             \
            const int off = it * 4096 + tid * 16;                                                      \
            const int row = off >> 7, cb = off & 127;                                                  \
            __builtin_amdgcn_global_load_lds((gptr1)(Ab + (size_t)(bm + row) * 2048 + (kbyte) + SWZ(row, cb)), \
                                             (lptr3)((dstA) + it * 4096 + wid * 1024), 16, 0, 0);      \
            __builtin_amdgcn_global_load_lds((gptr1)(Bb + (size_t)(bn + row) * 2048 + (kbyte) + SWZ(row, cb)), \
                                             (lptr3)((dstB) + it * 4096 + wid * 1024), 16, 0, 0);      \
        }                                                                                              \
    } while (0)

    FIN_STAGE(smem, smem + 16384, 0);
    for (int kt = 0; kt < 16; kt++) {
        char* Ac = smem + ((kt & 1) ? 8192 : 0);
        char* Bc = smem + 16384 + ((kt & 1) ? 8192 : 0);
        if (kt < 15) {
            char* An = smem + ((kt & 1) ? 0 : 8192);
            char* Bn = smem + 16384 + ((kt & 1) ? 0 : 8192);
            FIN_STAGE(An, Bn, (kt + 1) * 128);
            asm volatile("s_waitcnt vmcnt(4)" ::: "memory");
        } else {
            asm volatile("s_waitcnt vmcnt(0)" ::: "memory");
        }
        __builtin_amdgcn_s_barrier();
#pragma unroll
        for (int ks = 0; ks < 2; ks++) {
            short8 af[2], bfr[2];
#pragma unroll
            for (int m = 0; m < 2; m++)
                af[m] = ldfrag<128>(Ac, wr * 32 + m * 16 + r16, ks * 32 + g * 8);
#pragma unroll
            for (int n = 0; n < 2; n++)
                bfr[n] = ldfrag<128>(Bc, wc * 32 + n * 16 + r16, ks * 32 + g * 8);
#pragma unroll
            for (int m = 0; m < 2; m++)
#pragma unroll
                for (int n = 0; n < 2; n++)
                    acc[m][n] = __builtin_amdgcn_mfma_f32_16x16x32_bf16(af[m], bfr[n], acc[m][n], 0, 0, 0);
        }
        asm volatile("s_waitcnt lgkmcnt(0)" ::: "memory");
        __builtin_amdgcn_s_barrier();
    }
#undef FIN_STAGE
#pragma unroll
    for (int m = 0; m < 2; m++)
#pragma unroll
        for (int n = 0; n < 2; n++)
#pragma unroll
            for (int i = 0; i < 4; i++) {
                const int row = bm + wr * 32 + m * 16 + g * 4 + i;
                const int col = bn + wc * 32 + n * 16 + r16;
                C[(size_t)row * 1024 + col] = acc[m][n][i];
            }
}

extern "C" void kernel_launch(void* const* d_in, const int* in_sizes, int n_in,
                              void* d_out, int out_size, void* d_ws, size_t ws_size,
                              hipStream_t stream) {
    const float* x  = (const float*)d_in[0];
    const float* Wq = (const float*)d_in[1];
    const float* Wk = (const float*)d_in[2];
    const float* Wv = (const float*)d_in[3];
    const float* Wo = (const float*)d_in[4];
    const float* Kq = (const float*)d_in[5];
    const float* Kk = (const float*)d_in[6];
    float* out = (float*)d_out;
    float* ws = (float*)d_ws;

    const size_t M1 = 1024 * 1024;
    if (ws_size < 10 * M1 * sizeof(float)) return;

    __hip_bfloat16* xb  = (__hip_bfloat16*)(ws);                      // [0, 0.5M) f32 slots
    __hip_bfloat16* Wqt = (__hip_bfloat16*)(ws + M1 / 2);             // [0.5, 1)
    __hip_bfloat16* Wkt = (__hip_bfloat16*)(ws + 1 * M1);             // [1, 1.5)
    __hip_bfloat16* Wvt = (__hip_bfloat16*)(ws + 3 * M1 / 2);         // [1.5, 2)
    __hip_bfloat16* Wot = (__hip_bfloat16*)(ws + 2 * M1);             // [2, 2.5)
    __hip_bfloat16* KqT = (__hip_bfloat16*)(ws + 5 * M1 / 2);         // 64K elems
    __hip_bfloat16* KkT = (__hip_bfloat16*)(ws + 5 * M1 / 2 + 32768);
    __hip_bfloat16* VT  = (__hip_bfloat16*)(ws + 3 * M1);             // [3, 3.5)
    __hip_bfloat16* qfb = (__hip_bfloat16*)(ws + 7 * M1 / 2);         // [3.5, 4.5)
    __hip_bfloat16* kfb = (__hip_bfloat16*)(ws + 9 * M1 / 2);         // [4.5, 5.5)
    __hip_bfloat16* kfT = (__hip_bfloat16*)(ws + 11 * M1 / 2);        // [5.5, 6.5)
    __hip_bfloat16* Scb = (__hip_bfloat16*)(ws + 13 * M1 / 2);        // [6.5, 7.5)
    __hip_bfloat16* Spb = (__hip_bfloat16*)(ws + 15 * M1 / 2);        // [7.5, 8.5)
    __hip_bfloat16* Yb  = (__hip_bfloat16*)(ws + 17 * M1 / 2);        // [8.5, 9)
    float* ksum = ws + 9 * M1;                                        // 32K f32
    float* kp   = ws + 9 * M1 + 32768;                                // 32K f32

    prep<<<dim3(32, 32, 6), dim3(32, 8), 0, stream>>>(x, Wq, Wk, Wv, Wo, Kq, Kk,
                                                      xb, Wqt, Wkt, Wvt, Wot, KqT, KkT);
    qkv_feat<<<dim3(48, 8), 256, 0, stream>>>(xb, Wqt, Wkt, Wvt, KqT, KkT, qfb, kfb, kfT, VT);
    chunk_sums_mfma<<<dim3(NC, NH), 256, 0, stream>>>(kfT, VT, Scb, ksum);
    prefix_scan<<<dim3(NH, 8), 256, 0, stream>>>(Scb, Spb, ksum, kp);
    chunk_out_mfma<<<dim3(NC, NH), 256, 0, stream>>>(qfb, kfb, VT, Spb, kp, Yb);
    gemm_final<<<dim3(16, 16), 256, 0, stream>>>(Yb, Wot, out);
}